// Round 2
// baseline (3086.586 us; speedup 1.0000x reference)
//
#include <hip/hip_runtime.h>

#define USER_N 100000
#define ITEM_N 50000
#define NN (USER_N + ITEM_N)
#define D 64
#define IMGD 1024

// ---------------- GEMM: C[ITEM,64] = A[ITEM,1024] @ W[1024,64] + b ----------
__global__ __launch_bounds__(256) void gemm_feats(
    const float* __restrict__ A, const float* __restrict__ W,
    const float* __restrict__ b, float* __restrict__ C)
{
    __shared__ float As[64][17];
    __shared__ float Ws[16][64];
    const int row0 = blockIdx.x * 64;
    const int t = threadIdx.x;
    const int tx = t & 15, ty = t >> 4;
    float acc[4][4] = {};

    for (int k0 = 0; k0 < IMGD; k0 += 16) {
        // A tile: 64 rows x 16 k
        {
            const int kk = t & 15;
            const int r = t >> 4;  // 0..15
#pragma unroll
            for (int i = 0; i < 4; i++) {
                const int rr = r + i * 16;
                const int grow = row0 + rr;
                As[rr][kk] = (grow < ITEM_N) ? A[(size_t)grow * IMGD + k0 + kk] : 0.f;
            }
        }
        // W tile: 16 k x 64 cols
        {
            const int c = t & 63;
            const int kr0 = t >> 6;  // 0..3
#pragma unroll
            for (int i = 0; i < 4; i++) {
                const int kr = kr0 + i * 4;
                Ws[kr][c] = W[(size_t)(k0 + kr) * D + c];
            }
        }
        __syncthreads();
#pragma unroll
        for (int kk = 0; kk < 16; kk++) {
            float a[4], w[4];
#pragma unroll
            for (int i = 0; i < 4; i++) a[i] = As[ty * 4 + i][kk];
#pragma unroll
            for (int j = 0; j < 4; j++) w[j] = Ws[kk][tx * 4 + j];
#pragma unroll
            for (int i = 0; i < 4; i++)
#pragma unroll
                for (int j = 0; j < 4; j++) acc[i][j] += a[i] * w[j];
        }
        __syncthreads();
    }
    float4 bias = *reinterpret_cast<const float4*>(&b[tx * 4]);
#pragma unroll
    for (int i = 0; i < 4; i++) {
        const int grow = row0 + ty * 4 + i;
        if (grow < ITEM_N) {
            float4 v;
            v.x = acc[i][0] + bias.x;
            v.y = acc[i][1] + bias.y;
            v.z = acc[i][2] + bias.z;
            v.w = acc[i][3] + bias.w;
            *reinterpret_cast<float4*>(&C[(size_t)grow * D + tx * 4]) = v;
        }
    }
}

// ---------------- Row L2 normalize, one wave per row ------------------------
__global__ __launch_bounds__(256) void rownorm(float* __restrict__ X, int nrows)
{
    const int gid = blockIdx.x * blockDim.x + threadIdx.x;
    const int row = gid >> 6;
    const int lane = threadIdx.x & 63;
    if (row >= nrows) return;
    float v = X[(size_t)row * D + lane];
    float s = v * v;
#pragma unroll
    for (int o = 32; o > 0; o >>= 1) s += __shfl_xor(s, o, 64);
    const float scale = 1.0f / fmaxf(sqrtf(s), 1e-12f);
    X[(size_t)row * D + lane] = v * scale;
}

// ---------------- SPMM scatter-add: one wave per edge -----------------------
// x[c] = c < USER ? srcU[c] : srcI[c-USER]; out[r] += v * x[c]
__global__ __launch_bounds__(256) void spmm_atomic(
    const int* __restrict__ rows, const int* __restrict__ cols,
    const float* __restrict__ vals, int nnz,
    const float* __restrict__ srcU, const float* __restrict__ srcI,
    float* __restrict__ out)
{
    const long long gid = (long long)blockIdx.x * blockDim.x + threadIdx.x;
    const int e = (int)(gid >> 6);
    const int lane = threadIdx.x & 63;
    if (e >= nnz) return;
    const int r = rows[e];
    const int c = cols[e];
    const float v = vals[e];
    const float* src = (c < USER_N) ? (srcU + (size_t)c * D)
                                    : (srcI + (size_t)(c - USER_N) * D);
    atomicAdd(out + (size_t)r * D + lane, v * src[lane]);
}

// ---------------- o = a + b + c (float4) ------------------------------------
__global__ __launch_bounds__(256) void add3(
    const float4* __restrict__ a, const float4* __restrict__ b,
    const float4* __restrict__ c, float4* __restrict__ o, int n4)
{
    const int i = blockIdx.x * blockDim.x + threadIdx.x;
    if (i >= n4) return;
    float4 x = a[i], y = b[i], z = c[i];
    x.x += y.x + z.x;
    x.y += y.y + z.y;
    x.z += y.z + z.z;
    x.w += y.w + z.w;
    o[i] = x;
}

extern "C" void kernel_launch(void* const* d_in, const int* in_sizes, int n_in,
                              void* d_out, int out_size, void* d_ws, size_t ws_size,
                              hipStream_t stream)
{
    const int*   adj_rows = (const int*)d_in[0];
    const int*   adj_cols = (const int*)d_in[1];
    const float* adj_vals = (const float*)d_in[2];
    const int*   img_rows = (const int*)d_in[3];
    const int*   img_cols = (const int*)d_in[4];
    const float* img_vals = (const float*)d_in[5];
    const float* img_emb  = (const float*)d_in[6];
    const float* uEmb     = (const float*)d_in[7];
    const float* iEmb     = (const float*)d_in[8];
    const float* Wt       = (const float*)d_in[9];
    const float* bt       = (const float*)d_in[10];
    float* out = (float*)d_out;

    const int e_adj = in_sizes[0];
    const int e_img = in_sizes[3];

    float* featsN = (float*)d_ws;                    // ITEM*64
    float* bufA   = featsN + (size_t)ITEM_N * D;     // N*64
    float* bufB   = bufA + (size_t)NN * D;           // N*64

    const size_t ndbytes = (size_t)NN * D * sizeof(float);
    const int n4 = NN * D / 4;
    const int ADD_BLK = (n4 + 255) / 256;

    auto spmm_blocks = [](int nnz) { return (int)(((long long)nnz * 64 + 255) / 256); };

    // 1. embeds_img_adj -> bufA
    hipMemsetAsync(bufA, 0, ndbytes, stream);
    spmm_atomic<<<spmm_blocks(e_img), 256, 0, stream>>>(
        img_rows, img_cols, img_vals, e_img, uEmb, iEmb, bufA);

    // 2. image feats -> featsN, then normalize rows
    gemm_feats<<<(ITEM_N + 63) / 64, 256, 0, stream>>>(img_emb, Wt, bt, featsN);
    rownorm<<<(ITEM_N * 64 + 255) / 256, 256, 0, stream>>>(featsN, ITEM_N);

    // 3. e1 = spmm(adj; uEmb, featsN) -> bufB
    hipMemsetAsync(bufB, 0, ndbytes, stream);
    spmm_atomic<<<spmm_blocks(e_adj), 256, 0, stream>>>(
        adj_rows, adj_cols, adj_vals, e_adj, uEmb, featsN, bufB);

    // 4. e2 = spmm(adj; e1[:USER], iEmb) -> out (scratch)
    hipMemsetAsync(out, 0, ndbytes, stream);
    spmm_atomic<<<spmm_blocks(e_adj), 256, 0, stream>>>(
        adj_rows, adj_cols, adj_vals, e_adj, bufB, iEmb, out);

    // 5. E = e1 + e2 + img_adj -> bufA
    add3<<<ADD_BLK, 256, 0, stream>>>(
        (const float4*)bufA, (const float4*)bufB, (const float4*)out,
        (float4*)bufA, n4);

    // 6. cur1 = spmm(adj, E) -> bufB
    hipMemsetAsync(bufB, 0, ndbytes, stream);
    spmm_atomic<<<spmm_blocks(e_adj), 256, 0, stream>>>(
        adj_rows, adj_cols, adj_vals, e_adj, bufA, bufA + (size_t)USER_N * D, bufB);

    // 7. cur2 = spmm(adj, cur1) -> out
    hipMemsetAsync(out, 0, ndbytes, stream);
    spmm_atomic<<<spmm_blocks(e_adj), 256, 0, stream>>>(
        adj_rows, adj_cols, adj_vals, e_adj, bufB, bufB + (size_t)USER_N * D, out);

    // 8. out = E + cur1 + cur2
    add3<<<ADD_BLK, 256, 0, stream>>>(
        (const float4*)bufA, (const float4*)bufB, (const float4*)out,
        (float4*)out, n4);
}

// Round 3
// 1466.608 us; speedup vs baseline: 2.1046x; 2.1046x over previous
//
#include <hip/hip_runtime.h>

#define USER_N 100000
#define ITEM_N 50000
#define NN (USER_N + ITEM_N)
#define D 64
#define IMGD 1024

// ---------------- GEMM: C[ITEM,64] = A[ITEM,1024] @ W[1024,64] + b ----------
__global__ __launch_bounds__(256) void gemm_feats(
    const float* __restrict__ A, const float* __restrict__ W,
    const float* __restrict__ b, float* __restrict__ C)
{
    __shared__ float As[64][17];
    __shared__ float Ws[16][64];
    const int row0 = blockIdx.x * 64;
    const int t = threadIdx.x;
    const int tx = t & 15, ty = t >> 4;
    float acc[4][4] = {};

    for (int k0 = 0; k0 < IMGD; k0 += 16) {
        {
            const int kk = t & 15;
            const int r = t >> 4;
#pragma unroll
            for (int i = 0; i < 4; i++) {
                const int rr = r + i * 16;
                const int grow = row0 + rr;
                As[rr][kk] = (grow < ITEM_N) ? A[(size_t)grow * IMGD + k0 + kk] : 0.f;
            }
        }
        {
            const int c = t & 63;
            const int kr0 = t >> 6;
#pragma unroll
            for (int i = 0; i < 4; i++) {
                const int kr = kr0 + i * 4;
                Ws[kr][c] = W[(size_t)(k0 + kr) * D + c];
            }
        }
        __syncthreads();
#pragma unroll
        for (int kk = 0; kk < 16; kk++) {
            float a[4], w[4];
#pragma unroll
            for (int i = 0; i < 4; i++) a[i] = As[ty * 4 + i][kk];
#pragma unroll
            for (int j = 0; j < 4; j++) w[j] = Ws[kk][tx * 4 + j];
#pragma unroll
            for (int i = 0; i < 4; i++)
#pragma unroll
                for (int j = 0; j < 4; j++) acc[i][j] += a[i] * w[j];
        }
        __syncthreads();
    }
    float4 bias = *reinterpret_cast<const float4*>(&b[tx * 4]);
#pragma unroll
    for (int i = 0; i < 4; i++) {
        const int grow = row0 + ty * 4 + i;
        if (grow < ITEM_N) {
            float4 v;
            v.x = acc[i][0] + bias.x;
            v.y = acc[i][1] + bias.y;
            v.z = acc[i][2] + bias.z;
            v.w = acc[i][3] + bias.w;
            *reinterpret_cast<float4*>(&C[(size_t)grow * D + tx * 4]) = v;
        }
    }
}

// ---------------- Row L2 normalize, one wave per row ------------------------
__global__ __launch_bounds__(256) void rownorm(float* __restrict__ X, int nrows)
{
    const int gid = blockIdx.x * blockDim.x + threadIdx.x;
    const int row = gid >> 6;
    const int lane = threadIdx.x & 63;
    if (row >= nrows) return;
    float v = X[(size_t)row * D + lane];
    float s = v * v;
#pragma unroll
    for (int o = 32; o > 0; o >>= 1) s += __shfl_xor(s, o, 64);
    const float scale = 1.0f / fmaxf(sqrtf(s), 1e-12f);
    X[(size_t)row * D + lane] = v * scale;
}

// ================== CSR build: histogram -> scan -> scatter =================
__global__ __launch_bounds__(256) void hist_rows(
    const int* __restrict__ rows, int nnz, int* __restrict__ cnt)
{
    const int e = blockIdx.x * blockDim.x + threadIdx.x;
    if (e < nnz) atomicAdd(&cnt[rows[e]], 1);
}

// per-block exclusive scan; emits per-block totals
__global__ __launch_bounds__(1024) void scanA(
    const int* __restrict__ cnt, int* __restrict__ excl,
    int* __restrict__ blocksums, int n)
{
    const int t = threadIdx.x;
    const int gid = blockIdx.x * 1024 + t;
    const int lane = t & 63, wid = t >> 6;
    int v = (gid < n) ? cnt[gid] : 0;
    int x = v;
#pragma unroll
    for (int o = 1; o < 64; o <<= 1) {
        int y = __shfl_up(x, o, 64);
        if (lane >= o) x += y;
    }
    __shared__ int ws[16];
    __shared__ int wo[16];
    if (lane == 63) ws[wid] = x;
    __syncthreads();
    if (t < 16) {
        int s = ws[t];
        int xx = s;
#pragma unroll
        for (int o = 1; o < 16; o <<= 1) {
            int y = __shfl_up(xx, o, 16);
            if (t >= o) xx += y;
        }
        wo[t] = xx - s;
        if (t == 15) blocksums[blockIdx.x] = xx;
    }
    __syncthreads();
    if (gid < n) excl[gid] = x - v + wo[wid];
}

// single-block exclusive scan over block sums (nb <= 1024), in place
__global__ __launch_bounds__(1024) void scanB(int* __restrict__ bs, int nb)
{
    const int t = threadIdx.x;
    const int lane = t & 63, wid = t >> 6;
    int v = (t < nb) ? bs[t] : 0;
    int x = v;
#pragma unroll
    for (int o = 1; o < 64; o <<= 1) {
        int y = __shfl_up(x, o, 64);
        if (lane >= o) x += y;
    }
    __shared__ int ws[16];
    __shared__ int wo[16];
    if (lane == 63) ws[wid] = x;
    __syncthreads();
    if (t < 16) {
        int s = ws[t];
        int xx = s;
#pragma unroll
        for (int o = 1; o < 16; o <<= 1) {
            int y = __shfl_up(xx, o, 16);
            if (t >= o) xx += y;
        }
        wo[t] = xx - s;
    }
    __syncthreads();
    if (t < nb) bs[t] = x - v + wo[wid];
}

// add block offsets, produce row_ptr + cursor copy, set row_ptr[n]=nnz
__global__ __launch_bounds__(256) void scanC(
    int* __restrict__ rp, int* __restrict__ cursor,
    const int* __restrict__ bo, int n, int nnz)
{
    const int gid = blockIdx.x * blockDim.x + threadIdx.x;
    if (gid < n) {
        const int v = rp[gid] + bo[gid >> 10];
        rp[gid] = v;
        cursor[gid] = v;
    }
    if (gid == n) rp[n] = nnz;
}

__global__ __launch_bounds__(256) void scatter_edges(
    const int* __restrict__ rows, const int* __restrict__ cols,
    const float* __restrict__ vals, int nnz, int* __restrict__ cursor,
    int* __restrict__ cols_p, float* __restrict__ vals_p)
{
    const int e = blockIdx.x * blockDim.x + threadIdx.x;
    if (e >= nnz) return;
    const int pos = atomicAdd(&cursor[rows[e]], 1);
    cols_p[pos] = cols[e];
    vals_p[pos] = vals[e];
}

// ---------------- CSR SPMM: one wave per row, no atomics --------------------
// out[row] = sum_e val*x[col]  (+ add1[row] + add2[row] if non-null)
__global__ __launch_bounds__(256) void spmm_csr(
    const int* __restrict__ rp, const int* __restrict__ cols_p,
    const float* __restrict__ vals_p,
    const float* __restrict__ srcU, const float* __restrict__ srcI,
    float* __restrict__ out,
    const float* __restrict__ add1, const float* __restrict__ add2)
{
    const int gid = blockIdx.x * blockDim.x + threadIdx.x;
    const int row = gid >> 6;
    const int lane = threadIdx.x & 63;
    if (row >= NN) return;
    const int s = rp[row], e = rp[row + 1];
    float acc = 0.f;
    int i = s;
    for (; i + 1 < e; i += 2) {
        const int c0 = cols_p[i], c1 = cols_p[i + 1];
        const float v0 = vals_p[i], v1 = vals_p[i + 1];
        const float* s0 = (c0 < USER_N) ? (srcU + (size_t)c0 * D)
                                        : (srcI + (size_t)(c0 - USER_N) * D);
        const float* s1 = (c1 < USER_N) ? (srcU + (size_t)c1 * D)
                                        : (srcI + (size_t)(c1 - USER_N) * D);
        const float x0 = s0[lane], x1 = s1[lane];
        acc += v0 * x0;
        acc += v1 * x1;
    }
    if (i < e) {
        const int c = cols_p[i];
        const float v = vals_p[i];
        const float* sp = (c < USER_N) ? (srcU + (size_t)c * D)
                                       : (srcI + (size_t)(c - USER_N) * D);
        acc += v * sp[lane];
    }
    const size_t idx = (size_t)row * D + lane;
    if (add1) acc += add1[idx];
    if (add2) acc += add2[idx];
    out[idx] = acc;
}

// ---------------- fallback: atomic scatter spmm (round-2 proven) ------------
__global__ __launch_bounds__(256) void spmm_atomic(
    const int* __restrict__ rows, const int* __restrict__ cols,
    const float* __restrict__ vals, int nnz,
    const float* __restrict__ srcU, const float* __restrict__ srcI,
    float* __restrict__ out)
{
    const long long gid = (long long)blockIdx.x * blockDim.x + threadIdx.x;
    const int e = (int)(gid >> 6);
    const int lane = threadIdx.x & 63;
    if (e >= nnz) return;
    const int r = rows[e];
    const int c = cols[e];
    const float v = vals[e];
    const float* src = (c < USER_N) ? (srcU + (size_t)c * D)
                                    : (srcI + (size_t)(c - USER_N) * D);
    atomicAdd(out + (size_t)r * D + lane, v * src[lane]);
}

__global__ __launch_bounds__(256) void add3(
    const float4* __restrict__ a, const float4* __restrict__ b,
    const float4* __restrict__ c, float4* __restrict__ o, int n4)
{
    const int i = blockIdx.x * blockDim.x + threadIdx.x;
    if (i >= n4) return;
    float4 x = a[i], y = b[i], z = c[i];
    x.x += y.x + z.x;
    x.y += y.y + z.y;
    x.z += y.z + z.z;
    x.w += y.w + z.w;
    o[i] = x;
}

extern "C" void kernel_launch(void* const* d_in, const int* in_sizes, int n_in,
                              void* d_out, int out_size, void* d_ws, size_t ws_size,
                              hipStream_t stream)
{
    const int*   adj_rows = (const int*)d_in[0];
    const int*   adj_cols = (const int*)d_in[1];
    const float* adj_vals = (const float*)d_in[2];
    const int*   img_rows = (const int*)d_in[3];
    const int*   img_cols = (const int*)d_in[4];
    const float* img_vals = (const float*)d_in[5];
    const float* img_emb  = (const float*)d_in[6];
    const float* uEmb     = (const float*)d_in[7];
    const float* iEmb     = (const float*)d_in[8];
    const float* Wt       = (const float*)d_in[9];
    const float* bt       = (const float*)d_in[10];
    float* out = (float*)d_out;

    const int e_adj = in_sizes[0];
    const int e_img = in_sizes[3];

    const size_t ndfloats = (size_t)NN * D;
    const size_t ndbytes = ndfloats * sizeof(float);

    // ---- workspace layout (CSR path) ----
    size_t off = 0;
    auto carve = [&](size_t bytes) { size_t p = off; off += (bytes + 15) & ~(size_t)15; return p; };
    char* base = (char*)d_ws;
    const size_t o_featsN  = carve((size_t)ITEM_N * D * sizeof(float));
    const size_t o_bufA    = carve(ndbytes);
    const size_t o_bufB    = carve(ndbytes);
    const size_t o_rpAdj   = carve((NN + 1) * sizeof(int));
    const size_t o_rpImg   = carve((NN + 1) * sizeof(int));
    const size_t o_cursor  = carve(NN * sizeof(int));
    const size_t o_bsums   = carve(1024 * sizeof(int));
    const size_t o_colsAdj = carve((size_t)e_adj * sizeof(int));
    const size_t o_valsAdj = carve((size_t)e_adj * sizeof(float));
    const size_t o_colsImg = carve((size_t)e_img * sizeof(int));
    const size_t o_valsImg = carve((size_t)e_img * sizeof(float));
    const size_t csr_need = off;

    const int NB = (NN + 1023) / 1024;  // scanA blocks (147)

    if (ws_size >= csr_need) {
        float* featsN = (float*)(base + o_featsN);
        float* bufA   = (float*)(base + o_bufA);
        float* bufB   = (float*)(base + o_bufB);
        int* rpAdj    = (int*)(base + o_rpAdj);
        int* rpImg    = (int*)(base + o_rpImg);
        int* cursor   = (int*)(base + o_cursor);
        int* bsums    = (int*)(base + o_bsums);
        int* colsAdj  = (int*)(base + o_colsAdj);
        float* valsAdj= (float*)(base + o_valsAdj);
        int* colsImg  = (int*)(base + o_colsImg);
        float* valsImg= (float*)(base + o_valsImg);

        // ---- build CSR for adj ----
        hipMemsetAsync(rpAdj, 0, NN * sizeof(int), stream);
        hist_rows<<<(e_adj + 255) / 256, 256, 0, stream>>>(adj_rows, e_adj, rpAdj);
        scanA<<<NB, 1024, 0, stream>>>(rpAdj, rpAdj, bsums, NN);
        scanB<<<1, 1024, 0, stream>>>(bsums, NB);
        scanC<<<(NN + 256) / 256, 256, 0, stream>>>(rpAdj, cursor, bsums, NN, e_adj);
        scatter_edges<<<(e_adj + 255) / 256, 256, 0, stream>>>(
            adj_rows, adj_cols, adj_vals, e_adj, cursor, colsAdj, valsAdj);

        // ---- build CSR for img ----
        hipMemsetAsync(rpImg, 0, NN * sizeof(int), stream);
        hist_rows<<<(e_img + 255) / 256, 256, 0, stream>>>(img_rows, e_img, rpImg);
        scanA<<<NB, 1024, 0, stream>>>(rpImg, rpImg, bsums, NN);
        scanB<<<1, 1024, 0, stream>>>(bsums, NB);
        scanC<<<(NN + 256) / 256, 256, 0, stream>>>(rpImg, cursor, bsums, NN, e_img);
        scatter_edges<<<(e_img + 255) / 256, 256, 0, stream>>>(
            img_rows, img_cols, img_vals, e_img, cursor, colsImg, valsImg);

        // ---- dense feats ----
        gemm_feats<<<(ITEM_N + 63) / 64, 256, 0, stream>>>(img_emb, Wt, bt, featsN);
        rownorm<<<(ITEM_N * 64 + 255) / 256, 256, 0, stream>>>(featsN, ITEM_N);

        const int SPMM_GRID = (NN * 64 + 255) / 256;

        // g = img_adj @ [u;i] -> bufA
        spmm_csr<<<SPMM_GRID, 256, 0, stream>>>(
            rpImg, colsImg, valsImg, uEmb, iEmb, bufA, nullptr, nullptr);

        // e1 = adj @ [u; featsN] -> bufB
        spmm_csr<<<SPMM_GRID, 256, 0, stream>>>(
            rpAdj, colsAdj, valsAdj, uEmb, featsN, bufB, nullptr, nullptr);

        // E = adj @ [e1_U; i] + e1 + g -> bufA (in-place add2 read is per-element)
        spmm_csr<<<SPMM_GRID, 256, 0, stream>>>(
            rpAdj, colsAdj, valsAdj, bufB, iEmb, bufA, bufB, bufA);

        // cur1 = adj @ E -> bufB
        spmm_csr<<<SPMM_GRID, 256, 0, stream>>>(
            rpAdj, colsAdj, valsAdj, bufA, bufA + (size_t)USER_N * D, bufB,
            nullptr, nullptr);

        // out = adj @ cur1 + E + cur1
        spmm_csr<<<SPMM_GRID, 256, 0, stream>>>(
            rpAdj, colsAdj, valsAdj, bufB, bufB + (size_t)USER_N * D, out,
            bufA, bufB);
        return;
    }

    // ================= fallback: atomic path (round-2) ======================
    float* featsN = (float*)d_ws;
    float* bufA   = featsN + (size_t)ITEM_N * D;
    float* bufB   = bufA + ndfloats;

    const int n4 = NN * D / 4;
    const int ADD_BLK = (n4 + 255) / 256;
    auto spmm_blocks = [](int nnz) { return (int)(((long long)nnz * 64 + 255) / 256); };

    hipMemsetAsync(bufA, 0, ndbytes, stream);
    spmm_atomic<<<spmm_blocks(e_img), 256, 0, stream>>>(
        img_rows, img_cols, img_vals, e_img, uEmb, iEmb, bufA);
    gemm_feats<<<(ITEM_N + 63) / 64, 256, 0, stream>>>(img_emb, Wt, bt, featsN);
    rownorm<<<(ITEM_N * 64 + 255) / 256, 256, 0, stream>>>(featsN, ITEM_N);
    hipMemsetAsync(bufB, 0, ndbytes, stream);
    spmm_atomic<<<spmm_blocks(e_adj), 256, 0, stream>>>(
        adj_rows, adj_cols, adj_vals, e_adj, uEmb, featsN, bufB);
    hipMemsetAsync(out, 0, ndbytes, stream);
    spmm_atomic<<<spmm_blocks(e_adj), 256, 0, stream>>>(
        adj_rows, adj_cols, adj_vals, e_adj, bufB, iEmb, out);
    add3<<<ADD_BLK, 256, 0, stream>>>(
        (const float4*)bufA, (const float4*)bufB, (const float4*)out,
        (float4*)bufA, n4);
    hipMemsetAsync(bufB, 0, ndbytes, stream);
    spmm_atomic<<<spmm_blocks(e_adj), 256, 0, stream>>>(
        adj_rows, adj_cols, adj_vals, e_adj, bufA, bufA + (size_t)USER_N * D, bufB);
    hipMemsetAsync(out, 0, ndbytes, stream);
    spmm_atomic<<<spmm_blocks(e_adj), 256, 0, stream>>>(
        adj_rows, adj_cols, adj_vals, e_adj, bufB, bufB + (size_t)USER_N * D, out);
    add3<<<ADD_BLK, 256, 0, stream>>>(
        (const float4*)bufA, (const float4*)bufB, (const float4*)out,
        (float4*)out, n4);
}

// Round 4
// 1440.807 us; speedup vs baseline: 2.1423x; 1.0179x over previous
//
#include <hip/hip_runtime.h>

#define USER_N 100000
#define ITEM_N 50000
#define NN (USER_N + ITEM_N)
#define D 64
#define IMGD 1024
#define BK 64
#define LDP 68  // LDS row stride (floats): 64 + 4 pad, keeps 16B alignment

// ---------------- GEMM: C[ITEM,64] = A[ITEM,1024] @ W[1024,64] + b ----------
// 64x64 tile, BK=64. A staged k-major (At[k][row]) so fragments read as float4.
__global__ __launch_bounds__(256) void gemm_feats(
    const float* __restrict__ A, const float* __restrict__ W,
    const float* __restrict__ b, float* __restrict__ C)
{
    __shared__ float At[BK][LDP];
    __shared__ float Ws[BK][LDP];
    const int row0 = blockIdx.x * 64;
    const int t = threadIdx.x;
    const int tx = t & 15, ty = t >> 4;   // tx: col quad, ty: row quad
    float acc[4][4] = {};

    const int lr = t >> 4;        // load row 0..15 (+16 steps)
    const int lk = (t & 15) * 4;  // load k quad

    for (int k0 = 0; k0 < IMGD; k0 += BK) {
#pragma unroll
        for (int i = 0; i < 4; i++) {
            const int r = lr + i * 16;
            const int grow = row0 + r;
            float4 v = make_float4(0.f, 0.f, 0.f, 0.f);
            if (grow < ITEM_N)
                v = *reinterpret_cast<const float4*>(&A[(size_t)grow * IMGD + k0 + lk]);
            At[lk + 0][r] = v.x;
            At[lk + 1][r] = v.y;
            At[lk + 2][r] = v.z;
            At[lk + 3][r] = v.w;
        }
#pragma unroll
        for (int i = 0; i < 4; i++) {
            const int kr = lr + i * 16;
            float4 v = *reinterpret_cast<const float4*>(&W[(size_t)(k0 + kr) * D + lk]);
            *reinterpret_cast<float4*>(&Ws[kr][lk]) = v;
        }
        __syncthreads();
#pragma unroll 8
        for (int kk = 0; kk < BK; kk++) {
            const float4 a4 = *reinterpret_cast<const float4*>(&At[kk][ty * 4]);
            const float4 w4 = *reinterpret_cast<const float4*>(&Ws[kk][tx * 4]);
            const float a[4] = {a4.x, a4.y, a4.z, a4.w};
            const float w[4] = {w4.x, w4.y, w4.z, w4.w};
#pragma unroll
            for (int i = 0; i < 4; i++)
#pragma unroll
                for (int j = 0; j < 4; j++) acc[i][j] += a[i] * w[j];
        }
        __syncthreads();
    }
    const float4 bias = *reinterpret_cast<const float4*>(&b[tx * 4]);
#pragma unroll
    for (int i = 0; i < 4; i++) {
        const int grow = row0 + ty * 4 + i;
        if (grow < ITEM_N) {
            float4 v;
            v.x = acc[i][0] + bias.x;
            v.y = acc[i][1] + bias.y;
            v.z = acc[i][2] + bias.z;
            v.w = acc[i][3] + bias.w;
            *reinterpret_cast<float4*>(&C[(size_t)grow * D + tx * 4]) = v;
        }
    }
}

// ---------------- Row L2 normalize, one wave per row ------------------------
__global__ __launch_bounds__(256) void rownorm(float* __restrict__ X, int nrows)
{
    const int gid = blockIdx.x * blockDim.x + threadIdx.x;
    const int row = gid >> 6;
    const int lane = threadIdx.x & 63;
    if (row >= nrows) return;
    float v = X[(size_t)row * D + lane];
    float s = v * v;
#pragma unroll
    for (int o = 32; o > 0; o >>= 1) s += __shfl_xor(s, o, 64);
    const float scale = 1.0f / fmaxf(sqrtf(s), 1e-12f);
    X[(size_t)row * D + lane] = v * scale;
}

// ================== CSR build: histogram -> scan -> scatter =================
__global__ __launch_bounds__(256) void hist_rows(
    const int* __restrict__ rows, int nnz, int* __restrict__ cnt)
{
    const int e = blockIdx.x * blockDim.x + threadIdx.x;
    if (e < nnz) atomicAdd(&cnt[rows[e]], 1);
}

__global__ __launch_bounds__(1024) void scanA(
    const int* __restrict__ cnt, int* __restrict__ excl,
    int* __restrict__ blocksums, int n)
{
    const int t = threadIdx.x;
    const int gid = blockIdx.x * 1024 + t;
    const int lane = t & 63, wid = t >> 6;
    int v = (gid < n) ? cnt[gid] : 0;
    int x = v;
#pragma unroll
    for (int o = 1; o < 64; o <<= 1) {
        int y = __shfl_up(x, o, 64);
        if (lane >= o) x += y;
    }
    __shared__ int ws[16];
    __shared__ int wo[16];
    if (lane == 63) ws[wid] = x;
    __syncthreads();
    if (t < 16) {
        int s = ws[t];
        int xx = s;
#pragma unroll
        for (int o = 1; o < 16; o <<= 1) {
            int y = __shfl_up(xx, o, 16);
            if (t >= o) xx += y;
        }
        wo[t] = xx - s;
        if (t == 15) blocksums[blockIdx.x] = xx;
    }
    __syncthreads();
    if (gid < n) excl[gid] = x - v + wo[wid];
}

__global__ __launch_bounds__(1024) void scanB(int* __restrict__ bs, int nb)
{
    const int t = threadIdx.x;
    const int lane = t & 63, wid = t >> 6;
    int v = (t < nb) ? bs[t] : 0;
    int x = v;
#pragma unroll
    for (int o = 1; o < 64; o <<= 1) {
        int y = __shfl_up(x, o, 64);
        if (lane >= o) x += y;
    }
    __shared__ int ws[16];
    __shared__ int wo[16];
    if (lane == 63) ws[wid] = x;
    __syncthreads();
    if (t < 16) {
        int s = ws[t];
        int xx = s;
#pragma unroll
        for (int o = 1; o < 16; o <<= 1) {
            int y = __shfl_up(xx, o, 16);
            if (t >= o) xx += y;
        }
        wo[t] = xx - s;
    }
    __syncthreads();
    if (t < nb) bs[t] = x - v + wo[wid];
}

__global__ __launch_bounds__(256) void scanC(
    int* __restrict__ rp, int* __restrict__ cursor,
    const int* __restrict__ bo, int n, int nnz)
{
    const int gid = blockIdx.x * blockDim.x + threadIdx.x;
    if (gid < n) {
        const int v = rp[gid] + bo[gid >> 10];
        rp[gid] = v;
        cursor[gid] = v;
    }
    if (gid == n) rp[n] = nnz;
}

// scatter (col,val) as a single 8B record -> one cache-line touch per edge
__global__ __launch_bounds__(256) void scatter_edges(
    const int* __restrict__ rows, const int* __restrict__ cols,
    const float* __restrict__ vals, int nnz, int* __restrict__ cursor,
    int2* __restrict__ ev)
{
    const int e = blockIdx.x * blockDim.x + threadIdx.x;
    if (e >= nnz) return;
    const int pos = atomicAdd(&cursor[rows[e]], 1);
    ev[pos] = make_int2(cols[e], __float_as_int(vals[e]));
}

// ---------------- CSR SPMM: one wave per row, no atomics --------------------
__global__ __launch_bounds__(256) void spmm_csr(
    const int* __restrict__ rp, const int2* __restrict__ ev,
    const float* __restrict__ srcU, const float* __restrict__ srcI,
    float* __restrict__ out,
    const float* __restrict__ add1, const float* __restrict__ add2)
{
    const int gid = blockIdx.x * blockDim.x + threadIdx.x;
    const int row = gid >> 6;
    const int lane = threadIdx.x & 63;
    if (row >= NN) return;
    const int s = rp[row], e = rp[row + 1];
    float acc = 0.f;
    int i = s;
    for (; i + 1 < e; i += 2) {
        const int2 e0 = ev[i], e1 = ev[i + 1];
        const int c0 = e0.x, c1 = e1.x;
        const float v0 = __int_as_float(e0.y), v1 = __int_as_float(e1.y);
        const float* s0 = (c0 < USER_N) ? (srcU + (size_t)c0 * D)
                                        : (srcI + (size_t)(c0 - USER_N) * D);
        const float* s1 = (c1 < USER_N) ? (srcU + (size_t)c1 * D)
                                        : (srcI + (size_t)(c1 - USER_N) * D);
        acc += v0 * s0[lane];
        acc += v1 * s1[lane];
    }
    if (i < e) {
        const int2 e0 = ev[i];
        const float* sp = (e0.x < USER_N) ? (srcU + (size_t)e0.x * D)
                                          : (srcI + (size_t)(e0.x - USER_N) * D);
        acc += __int_as_float(e0.y) * sp[lane];
    }
    const size_t idx = (size_t)row * D + lane;
    if (add1) acc += add1[idx];
    if (add2) acc += add2[idx];
    out[idx] = acc;
}

extern "C" void kernel_launch(void* const* d_in, const int* in_sizes, int n_in,
                              void* d_out, int out_size, void* d_ws, size_t ws_size,
                              hipStream_t stream)
{
    const int*   adj_rows = (const int*)d_in[0];
    const int*   adj_cols = (const int*)d_in[1];
    const float* adj_vals = (const float*)d_in[2];
    const int*   img_rows = (const int*)d_in[3];
    const int*   img_cols = (const int*)d_in[4];
    const float* img_vals = (const float*)d_in[5];
    const float* img_emb  = (const float*)d_in[6];
    const float* uEmb     = (const float*)d_in[7];
    const float* iEmb     = (const float*)d_in[8];
    const float* Wt       = (const float*)d_in[9];
    const float* bt       = (const float*)d_in[10];
    float* out = (float*)d_out;

    const int e_adj = in_sizes[0];
    const int e_img = in_sizes[3];

    const size_t ndbytes = (size_t)NN * D * sizeof(float);

    // ---- workspace layout ----
    size_t off = 0;
    auto carve = [&](size_t bytes) { size_t p = off; off += (bytes + 15) & ~(size_t)15; return p; };
    char* base = (char*)d_ws;
    const size_t o_featsN = carve((size_t)ITEM_N * D * sizeof(float));
    const size_t o_bufA   = carve(ndbytes);
    const size_t o_bufB   = carve(ndbytes);
    const size_t o_rpAdj  = carve((NN + 1) * sizeof(int));
    const size_t o_rpImg  = carve((NN + 1) * sizeof(int));
    const size_t o_cursor = carve(NN * sizeof(int));
    const size_t o_bsums  = carve(1024 * sizeof(int));
    const size_t o_evAdj  = carve((size_t)e_adj * sizeof(int2));
    const size_t o_evImg  = carve((size_t)e_img * sizeof(int2));
    const size_t need = off;
    if (ws_size < need) return;  // (benched configs provide enough)

    float* featsN = (float*)(base + o_featsN);
    float* bufA   = (float*)(base + o_bufA);
    float* bufB   = (float*)(base + o_bufB);
    int* rpAdj    = (int*)(base + o_rpAdj);
    int* rpImg    = (int*)(base + o_rpImg);
    int* cursor   = (int*)(base + o_cursor);
    int* bsums    = (int*)(base + o_bsums);
    int2* evAdj   = (int2*)(base + o_evAdj);
    int2* evImg   = (int2*)(base + o_evImg);

    const int NB = (NN + 1023) / 1024;

    // ---- build CSR for adj ----
    hipMemsetAsync(rpAdj, 0, NN * sizeof(int), stream);
    hist_rows<<<(e_adj + 255) / 256, 256, 0, stream>>>(adj_rows, e_adj, rpAdj);
    scanA<<<NB, 1024, 0, stream>>>(rpAdj, rpAdj, bsums, NN);
    scanB<<<1, 1024, 0, stream>>>(bsums, NB);
    scanC<<<(NN + 256) / 256, 256, 0, stream>>>(rpAdj, cursor, bsums, NN, e_adj);
    scatter_edges<<<(e_adj + 255) / 256, 256, 0, stream>>>(
        adj_rows, adj_cols, adj_vals, e_adj, cursor, evAdj);

    // ---- build CSR for img ----
    hipMemsetAsync(rpImg, 0, NN * sizeof(int), stream);
    hist_rows<<<(e_img + 255) / 256, 256, 0, stream>>>(img_rows, e_img, rpImg);
    scanA<<<NB, 1024, 0, stream>>>(rpImg, rpImg, bsums, NN);
    scanB<<<1, 1024, 0, stream>>>(bsums, NB);
    scanC<<<(NN + 256) / 256, 256, 0, stream>>>(rpImg, cursor, bsums, NN, e_img);
    scatter_edges<<<(e_img + 255) / 256, 256, 0, stream>>>(
        img_rows, img_cols, img_vals, e_img, cursor, evImg);

    // ---- dense feats ----
    gemm_feats<<<(ITEM_N + 63) / 64, 256, 0, stream>>>(img_emb, Wt, bt, featsN);
    rownorm<<<(ITEM_N * 64 + 255) / 256, 256, 0, stream>>>(featsN, ITEM_N);

    const int SPMM_GRID = (NN * 64 + 255) / 256;

    // g = img_adj @ [u;i] -> bufA
    spmm_csr<<<SPMM_GRID, 256, 0, stream>>>(
        rpImg, evImg, uEmb, iEmb, bufA, nullptr, nullptr);

    // e1 = adj @ [u; featsN] -> bufB
    spmm_csr<<<SPMM_GRID, 256, 0, stream>>>(
        rpAdj, evAdj, uEmb, featsN, bufB, nullptr, nullptr);

    // E = adj @ [e1_U; i] + e1 + g -> bufA
    spmm_csr<<<SPMM_GRID, 256, 0, stream>>>(
        rpAdj, evAdj, bufB, iEmb, bufA, bufB, bufA);

    // cur1 = adj @ E -> bufB
    spmm_csr<<<SPMM_GRID, 256, 0, stream>>>(
        rpAdj, evAdj, bufA, bufA + (size_t)USER_N * D, bufB, nullptr, nullptr);

    // out = adj @ cur1 + E + cur1
    spmm_csr<<<SPMM_GRID, 256, 0, stream>>>(
        rpAdj, evAdj, bufB, bufB + (size_t)USER_N * D, out, bufA, bufB);
}

// Round 5
// 896.476 us; speedup vs baseline: 3.4430x; 1.6072x over previous
//
#include <hip/hip_runtime.h>

#define USER_N 100000
#define ITEM_N 50000
#define NN (USER_N + ITEM_N)
#define D 64
#define IMGD 1024
#define BK 64
#define LDP 68

#define BUCKET_BITS 10
#define BROWS (1 << BUCKET_BITS)          // 1024 rows per bucket
#define NBUCK ((NN + BROWS - 1) >> BUCKET_BITS)   // 147
#define CHUNK 4096

// ---------------- GEMM: C[ITEM,64] = A[ITEM,1024] @ W[1024,64] + b ----------
__global__ __launch_bounds__(256) void gemm_feats(
    const float* __restrict__ A, const float* __restrict__ W,
    const float* __restrict__ b, float* __restrict__ C)
{
    __shared__ float At[BK][LDP];
    __shared__ float Ws[BK][LDP];
    const int row0 = blockIdx.x * 64;
    const int t = threadIdx.x;
    const int tx = t & 15, ty = t >> 4;
    float acc[4][4] = {};

    const int lr = t >> 4;
    const int lk = (t & 15) * 4;

    for (int k0 = 0; k0 < IMGD; k0 += BK) {
#pragma unroll
        for (int i = 0; i < 4; i++) {
            const int r = lr + i * 16;
            const int grow = row0 + r;
            float4 v = make_float4(0.f, 0.f, 0.f, 0.f);
            if (grow < ITEM_N)
                v = *reinterpret_cast<const float4*>(&A[(size_t)grow * IMGD + k0 + lk]);
            At[lk + 0][r] = v.x;
            At[lk + 1][r] = v.y;
            At[lk + 2][r] = v.z;
            At[lk + 3][r] = v.w;
        }
#pragma unroll
        for (int i = 0; i < 4; i++) {
            const int kr = lr + i * 16;
            float4 v = *reinterpret_cast<const float4*>(&W[(size_t)(k0 + kr) * D + lk]);
            *reinterpret_cast<float4*>(&Ws[kr][lk]) = v;
        }
        __syncthreads();
#pragma unroll 8
        for (int kk = 0; kk < BK; kk++) {
            const float4 a4 = *reinterpret_cast<const float4*>(&At[kk][ty * 4]);
            const float4 w4 = *reinterpret_cast<const float4*>(&Ws[kk][tx * 4]);
            const float a[4] = {a4.x, a4.y, a4.z, a4.w};
            const float w[4] = {w4.x, w4.y, w4.z, w4.w};
#pragma unroll
            for (int i = 0; i < 4; i++)
#pragma unroll
                for (int j = 0; j < 4; j++) acc[i][j] += a[i] * w[j];
        }
        __syncthreads();
    }
    const float4 bias = *reinterpret_cast<const float4*>(&b[tx * 4]);
#pragma unroll
    for (int i = 0; i < 4; i++) {
        const int grow = row0 + ty * 4 + i;
        if (grow < ITEM_N) {
            float4 v;
            v.x = acc[i][0] + bias.x;
            v.y = acc[i][1] + bias.y;
            v.z = acc[i][2] + bias.z;
            v.w = acc[i][3] + bias.w;
            *reinterpret_cast<float4*>(&C[(size_t)grow * D + tx * 4]) = v;
        }
    }
}

// ---------------- Row L2 normalize ------------------------------------------
__global__ __launch_bounds__(256) void rownorm(float* __restrict__ X, int nrows)
{
    const int gid = blockIdx.x * blockDim.x + threadIdx.x;
    const int row = gid >> 6;
    const int lane = threadIdx.x & 63;
    if (row >= nrows) return;
    float v = X[(size_t)row * D + lane];
    float s = v * v;
#pragma unroll
    for (int o = 32; o > 0; o >>= 1) s += __shfl_xor(s, o, 64);
    const float scale = 1.0f / fmaxf(sqrtf(s), 1e-12f);
    X[(size_t)row * D + lane] = v * scale;
}

// ============== CSR build via 2-level bucket sort (LDS atomics only) ========
// K1: per-block bucket histogram -> histT[bucket][block]
__global__ __launch_bounds__(256) void bucket_count(
    const int* __restrict__ rows, int nnz, int nb, int* __restrict__ histT)
{
    __shared__ int cnt[NBUCK];
    for (int i = threadIdx.x; i < NBUCK; i += 256) cnt[i] = 0;
    __syncthreads();
    const int e0 = blockIdx.x * CHUNK;
    const int e1 = min(e0 + CHUNK, nnz);
    for (int e = e0 + threadIdx.x; e < e1; e += 256)
        atomicAdd(&cnt[rows[e] >> BUCKET_BITS], 1);
    __syncthreads();
    for (int b = threadIdx.x; b < NBUCK; b += 256)
        histT[b * nb + blockIdx.x] = cnt[b];
}

// per-block exclusive scan; emits per-block totals
__global__ __launch_bounds__(1024) void scanA(
    const int* __restrict__ cnt, int* __restrict__ excl,
    int* __restrict__ blocksums, int n)
{
    const int t = threadIdx.x;
    const int gid = blockIdx.x * 1024 + t;
    const int lane = t & 63, wid = t >> 6;
    int v = (gid < n) ? cnt[gid] : 0;
    int x = v;
#pragma unroll
    for (int o = 1; o < 64; o <<= 1) {
        int y = __shfl_up(x, o, 64);
        if (lane >= o) x += y;
    }
    __shared__ int ws[16];
    __shared__ int wo[16];
    if (lane == 63) ws[wid] = x;
    __syncthreads();
    if (t < 16) {
        int s = ws[t];
        int xx = s;
#pragma unroll
        for (int o = 1; o < 16; o <<= 1) {
            int y = __shfl_up(xx, o, 16);
            if (t >= o) xx += y;
        }
        wo[t] = xx - s;
        if (t == 15) blocksums[blockIdx.x] = xx;
    }
    __syncthreads();
    if (gid < n) excl[gid] = x - v + wo[wid];
}

__global__ __launch_bounds__(1024) void scanB(int* __restrict__ bs, int nb)
{
    const int t = threadIdx.x;
    const int lane = t & 63, wid = t >> 6;
    int v = (t < nb) ? bs[t] : 0;
    int x = v;
#pragma unroll
    for (int o = 1; o < 64; o <<= 1) {
        int y = __shfl_up(x, o, 64);
        if (lane >= o) x += y;
    }
    __shared__ int ws[16];
    __shared__ int wo[16];
    if (lane == 63) ws[wid] = x;
    __syncthreads();
    if (t < 16) {
        int s = ws[t];
        int xx = s;
#pragma unroll
        for (int o = 1; o < 16; o <<= 1) {
            int y = __shfl_up(xx, o, 16);
            if (t >= o) xx += y;
        }
        wo[t] = xx - s;
    }
    __syncthreads();
    if (t < nb) bs[t] = x - v + wo[wid];
}

__global__ __launch_bounds__(256) void scan_apply(
    int* __restrict__ excl, const int* __restrict__ bo, int n)
{
    const int gid = blockIdx.x * blockDim.x + threadIdx.x;
    if (gid < n) excl[gid] += bo[gid >> 10];
}

// K3: place records bucket-contiguously. rec = {col<<10 | rowlow, valbits}
__global__ __launch_bounds__(256) void bucket_place(
    const int* __restrict__ rows, const int* __restrict__ cols,
    const float* __restrict__ vals, int nnz, int nb,
    const int* __restrict__ offsT, uint2* __restrict__ rec)
{
    __shared__ int cur[NBUCK];
    for (int b = threadIdx.x; b < NBUCK; b += 256)
        cur[b] = offsT[b * nb + blockIdx.x];
    __syncthreads();
    const int e0 = blockIdx.x * CHUNK;
    const int e1 = min(e0 + CHUNK, nnz);
    for (int e = e0 + threadIdx.x; e < e1; e += 256) {
        const int r = rows[e];
        const int b = r >> BUCKET_BITS;
        const int pos = atomicAdd(&cur[b], 1);
        rec[pos] = make_uint2(((unsigned)cols[e] << BUCKET_BITS) |
                                  (unsigned)(r & (BROWS - 1)),
                              __float_as_uint(vals[e]));
    }
}

// K4: one block per bucket: build rp + final (col,val) CSR within L2-resident
// window. LDS atomics only.
__global__ __launch_bounds__(1024) void bucket_finalize(
    const uint2* __restrict__ rec, int nnz, int nb,
    const int* __restrict__ offsT, int* __restrict__ rp,
    int2* __restrict__ ev)
{
    const int b = blockIdx.x;
    const int t = threadIdx.x;
    const int rlo = b << BUCKET_BITS;
    const int segs = offsT[b * nb];
    const int sege = (b + 1 < NBUCK) ? offsT[(b + 1) * nb] : nnz;

    __shared__ int cnt[BROWS];
    __shared__ int cur[BROWS];
    cnt[t] = 0;
    __syncthreads();
    for (int i = segs + t; i < sege; i += 1024)
        atomicAdd(&cnt[rec[i].x & (BROWS - 1)], 1);
    __syncthreads();

    // block exclusive scan over 1024 counters
    const int lane = t & 63, wid = t >> 6;
    const int v = cnt[t];
    int x = v;
#pragma unroll
    for (int o = 1; o < 64; o <<= 1) {
        int y = __shfl_up(x, o, 64);
        if (lane >= o) x += y;
    }
    __shared__ int wsum[16];
    __shared__ int woff[16];
    if (lane == 63) wsum[wid] = x;
    __syncthreads();
    if (t < 16) {
        int s = wsum[t];
        int xx = s;
#pragma unroll
        for (int o = 1; o < 16; o <<= 1) {
            int y = __shfl_up(xx, o, 16);
            if (t >= o) xx += y;
        }
        woff[t] = xx - s;
    }
    __syncthreads();
    const int start = segs + (x - v + woff[wid]);

    if (rlo + t < NN) rp[rlo + t] = start;
    if (b == NBUCK - 1 && t == 0) rp[NN] = nnz;
    cur[t] = start;
    __syncthreads();

    for (int i = segs + t; i < sege; i += 1024) {
        const uint2 R = rec[i];
        const int rl = (int)(R.x & (BROWS - 1));
        const int c = (int)(R.x >> BUCKET_BITS);
        const int pos = atomicAdd(&cur[rl], 1);
        ev[pos] = make_int2(c, (int)R.y);
    }
}

// ---------------- CSR SPMM: one wave per row, 4-edge MLP --------------------
__global__ __launch_bounds__(256) void spmm_csr(
    const int* __restrict__ rp, const int2* __restrict__ ev,
    const float* __restrict__ srcU, const float* __restrict__ srcI,
    float* __restrict__ out,
    const float* __restrict__ add1, const float* __restrict__ add2)
{
    const int gid = blockIdx.x * blockDim.x + threadIdx.x;
    const int row = gid >> 6;
    const int lane = threadIdx.x & 63;
    if (row >= NN) return;
    const int s = rp[row], e = rp[row + 1];
    float acc = 0.f;
    int i = s;
    for (; i + 3 < e; i += 4) {
        const int2 e0 = ev[i], e1 = ev[i + 1], e2 = ev[i + 2], e3 = ev[i + 3];
        const float* p0 = (e0.x < USER_N) ? (srcU + (size_t)e0.x * D)
                                          : (srcI + (size_t)(e0.x - USER_N) * D);
        const float* p1 = (e1.x < USER_N) ? (srcU + (size_t)e1.x * D)
                                          : (srcI + (size_t)(e1.x - USER_N) * D);
        const float* p2 = (e2.x < USER_N) ? (srcU + (size_t)e2.x * D)
                                          : (srcI + (size_t)(e2.x - USER_N) * D);
        const float* p3 = (e3.x < USER_N) ? (srcU + (size_t)e3.x * D)
                                          : (srcI + (size_t)(e3.x - USER_N) * D);
        const float x0 = p0[lane], x1 = p1[lane], x2 = p2[lane], x3 = p3[lane];
        acc += __int_as_float(e0.y) * x0;
        acc += __int_as_float(e1.y) * x1;
        acc += __int_as_float(e2.y) * x2;
        acc += __int_as_float(e3.y) * x3;
    }
    for (; i < e; i++) {
        const int2 e0 = ev[i];
        const float* p0 = (e0.x < USER_N) ? (srcU + (size_t)e0.x * D)
                                          : (srcI + (size_t)(e0.x - USER_N) * D);
        acc += __int_as_float(e0.y) * p0[lane];
    }
    const size_t idx = (size_t)row * D + lane;
    if (add1) acc += add1[idx];
    if (add2) acc += add2[idx];
    out[idx] = acc;
}

extern "C" void kernel_launch(void* const* d_in, const int* in_sizes, int n_in,
                              void* d_out, int out_size, void* d_ws, size_t ws_size,
                              hipStream_t stream)
{
    const int*   adj_rows = (const int*)d_in[0];
    const int*   adj_cols = (const int*)d_in[1];
    const float* adj_vals = (const float*)d_in[2];
    const int*   img_rows = (const int*)d_in[3];
    const int*   img_cols = (const int*)d_in[4];
    const float* img_vals = (const float*)d_in[5];
    const float* img_emb  = (const float*)d_in[6];
    const float* uEmb     = (const float*)d_in[7];
    const float* iEmb     = (const float*)d_in[8];
    const float* Wt       = (const float*)d_in[9];
    const float* bt       = (const float*)d_in[10];
    float* out = (float*)d_out;

    const int e_adj = in_sizes[0];
    const int e_img = in_sizes[3];

    const int NB_adj = (e_adj + CHUNK - 1) / CHUNK;
    const int NB_img = (e_img + CHUNK - 1) / CHUNK;

    const size_t ndbytes = (size_t)NN * D * sizeof(float);

    // ---- workspace layout ----
    size_t off = 0;
    auto carve = [&](size_t bytes) { size_t p = off; off += (bytes + 15) & ~(size_t)15; return p; };
    char* base = (char*)d_ws;
    const size_t o_featsN = carve((size_t)ITEM_N * D * sizeof(float));
    const size_t o_bufA   = carve(ndbytes);
    const size_t o_bufB   = carve(ndbytes);
    const size_t o_rpAdj  = carve((NN + 1) * sizeof(int));
    const size_t o_rpImg  = carve((NN + 1) * sizeof(int));
    const size_t o_bsums  = carve(1024 * sizeof(int));
    const size_t o_histT  = carve((size_t)NBUCK * (NB_adj > NB_img ? NB_adj : NB_img) * sizeof(int));
    const size_t o_rec    = carve((size_t)(e_adj > e_img ? e_adj : e_img) * sizeof(uint2));
    const size_t o_evAdj  = carve((size_t)e_adj * sizeof(int2));
    const size_t o_evImg  = carve((size_t)e_img * sizeof(int2));
    const size_t need = off;
    if (ws_size < need) return;

    float* featsN = (float*)(base + o_featsN);
    float* bufA   = (float*)(base + o_bufA);
    float* bufB   = (float*)(base + o_bufB);
    int* rpAdj    = (int*)(base + o_rpAdj);
    int* rpImg    = (int*)(base + o_rpImg);
    int* bsums    = (int*)(base + o_bsums);
    int* histT    = (int*)(base + o_histT);
    uint2* rec    = (uint2*)(base + o_rec);
    int2* evAdj   = (int2*)(base + o_evAdj);
    int2* evImg   = (int2*)(base + o_evImg);

    // ---- build CSR for adj (LDS-atomic bucket sort) ----
    {
        const int n = NBUCK * NB_adj;
        const int nsb = (n + 1023) / 1024;
        bucket_count<<<NB_adj, 256, 0, stream>>>(adj_rows, e_adj, NB_adj, histT);
        scanA<<<nsb, 1024, 0, stream>>>(histT, histT, bsums, n);
        scanB<<<1, 1024, 0, stream>>>(bsums, nsb);
        scan_apply<<<(n + 255) / 256, 256, 0, stream>>>(histT, bsums, n);
        bucket_place<<<NB_adj, 256, 0, stream>>>(
            adj_rows, adj_cols, adj_vals, e_adj, NB_adj, histT, rec);
        bucket_finalize<<<NBUCK, 1024, 0, stream>>>(
            rec, e_adj, NB_adj, histT, rpAdj, evAdj);
    }
    // ---- build CSR for img ----
    {
        const int n = NBUCK * NB_img;
        const int nsb = (n + 1023) / 1024;
        bucket_count<<<NB_img, 256, 0, stream>>>(img_rows, e_img, NB_img, histT);
        scanA<<<nsb, 1024, 0, stream>>>(histT, histT, bsums, n);
        scanB<<<1, 1024, 0, stream>>>(bsums, nsb);
        scan_apply<<<(n + 255) / 256, 256, 0, stream>>>(histT, bsums, n);
        bucket_place<<<NB_img, 256, 0, stream>>>(
            img_rows, img_cols, img_vals, e_img, NB_img, histT, rec);
        bucket_finalize<<<NBUCK, 1024, 0, stream>>>(
            rec, e_img, NB_img, histT, rpImg, evImg);
    }

    // ---- dense feats ----
    gemm_feats<<<(ITEM_N + 63) / 64, 256, 0, stream>>>(img_emb, Wt, bt, featsN);
    rownorm<<<(ITEM_N * 64 + 255) / 256, 256, 0, stream>>>(featsN, ITEM_N);

    const int SPMM_GRID = (NN * 64 + 255) / 256;

    // g = img_adj @ [u;i] -> bufA
    spmm_csr<<<SPMM_GRID, 256, 0, stream>>>(
        rpImg, evImg, uEmb, iEmb, bufA, nullptr, nullptr);

    // e1 = adj @ [u; featsN] -> bufB
    spmm_csr<<<SPMM_GRID, 256, 0, stream>>>(
        rpAdj, evAdj, uEmb, featsN, bufB, nullptr, nullptr);

    // E = adj @ [e1_U; i] + e1 + g -> bufA
    spmm_csr<<<SPMM_GRID, 256, 0, stream>>>(
        rpAdj, evAdj, bufB, iEmb, bufA, bufB, bufA);

    // cur1 = adj @ E -> bufB
    spmm_csr<<<SPMM_GRID, 256, 0, stream>>>(
        rpAdj, evAdj, bufA, bufA + (size_t)USER_N * D, bufB, nullptr, nullptr);

    // out = adj @ cur1 + E + cur1
    spmm_csr<<<SPMM_GRID, 256, 0, stream>>>(
        rpAdj, evAdj, bufB, bufB + (size_t)USER_N * D, out, bufA, bufB);
}

// Round 6
// 892.217 us; speedup vs baseline: 3.4595x; 1.0048x over previous
//
#include <hip/hip_runtime.h>
#include <hip/hip_fp16.h>

#define USER_N 100000
#define ITEM_N 50000
#define NN (USER_N + ITEM_N)
#define D 64
#define IMGD 1024
#define BK 64
#define LDP 68

#define BUCKET_BITS 10
#define BROWS (1 << BUCKET_BITS)
#define NBUCK ((NN + BROWS - 1) >> BUCKET_BITS)   // 147
#define CHUNK 4096

// ---------------- GEMM: C[ITEM,64] = A[ITEM,1024] @ W[1024,64] + b ----------
// A staged ROW-major (b128 stores, low conflict); inner loop in kb-blocks of 4
// so all LDS reads are b128 and <=2-way (free).
__global__ __launch_bounds__(256) void gemm_feats(
    const float* __restrict__ A, const float* __restrict__ W,
    const float* __restrict__ b, float* __restrict__ C)
{
    __shared__ float As[BK][LDP];   // [row][k]
    __shared__ float Ws[BK][LDP];   // [k][col]
    const int row0 = blockIdx.x * 64;
    const int t = threadIdx.x;
    const int tx = t & 15, ty = t >> 4;
    float acc[4][4] = {};

    const int lr = t >> 4;        // 0..15
    const int lk = (t & 15) * 4;  // 0..60

    for (int k0 = 0; k0 < IMGD; k0 += BK) {
#pragma unroll
        for (int i = 0; i < 4; i++) {
            const int r = lr + i * 16;
            const int grow = row0 + r;
            float4 v = make_float4(0.f, 0.f, 0.f, 0.f);
            if (grow < ITEM_N)
                v = *reinterpret_cast<const float4*>(&A[(size_t)grow * IMGD + k0 + lk]);
            *reinterpret_cast<float4*>(&As[r][lk]) = v;
        }
#pragma unroll
        for (int i = 0; i < 4; i++) {
            const int kr = lr + i * 16;
            float4 v = *reinterpret_cast<const float4*>(&W[(size_t)(k0 + kr) * D + lk]);
            *reinterpret_cast<float4*>(&Ws[kr][lk]) = v;
        }
        __syncthreads();
#pragma unroll
        for (int kb = 0; kb < BK / 4; kb++) {
            float a_[4][4], w_[4][4];
#pragma unroll
            for (int i = 0; i < 4; i++) {
                const float4 v = *reinterpret_cast<const float4*>(&As[ty * 4 + i][kb * 4]);
                a_[i][0] = v.x; a_[i][1] = v.y; a_[i][2] = v.z; a_[i][3] = v.w;
            }
#pragma unroll
            for (int j = 0; j < 4; j++) {
                const float4 v = *reinterpret_cast<const float4*>(&Ws[kb * 4 + j][tx * 4]);
                w_[j][0] = v.x; w_[j][1] = v.y; w_[j][2] = v.z; w_[j][3] = v.w;
            }
#pragma unroll
            for (int j = 0; j < 4; j++)       // k within block
#pragma unroll
                for (int i = 0; i < 4; i++)   // row
#pragma unroll
                    for (int c = 0; c < 4; c++)  // col
                        acc[i][c] += a_[i][j] * w_[j][c];
        }
        __syncthreads();
    }
    const float4 bias = *reinterpret_cast<const float4*>(&b[tx * 4]);
#pragma unroll
    for (int i = 0; i < 4; i++) {
        const int grow = row0 + ty * 4 + i;
        if (grow < ITEM_N) {
            float4 v;
            v.x = acc[i][0] + bias.x;
            v.y = acc[i][1] + bias.y;
            v.z = acc[i][2] + bias.z;
            v.w = acc[i][3] + bias.w;
            *reinterpret_cast<float4*>(&C[(size_t)grow * D + tx * 4]) = v;
        }
    }
}

// ------------- Row L2 normalize -> fp16 output (one wave per row) -----------
__global__ __launch_bounds__(256) void rownorm_h(
    const float* __restrict__ X, __half* __restrict__ Y, int nrows)
{
    const int gid = blockIdx.x * blockDim.x + threadIdx.x;
    const int row = gid >> 6;
    const int lane = threadIdx.x & 63;
    if (row >= nrows) return;
    float v = X[(size_t)row * D + lane];
    float s = v * v;
#pragma unroll
    for (int o = 32; o > 0; o >>= 1) s += __shfl_xor(s, o, 64);
    const float scale = 1.0f / fmaxf(sqrtf(s), 1e-12f);
    Y[(size_t)row * D + lane] = __float2half(v * scale);
}

// ------------- fp32 -> fp16 convert (float4 in, 2x half2 out) ---------------
__global__ __launch_bounds__(256) void cvt_f2h(
    const float* __restrict__ s, __half* __restrict__ d, int n4)
{
    const int i = blockIdx.x * blockDim.x + threadIdx.x;
    if (i >= n4) return;
    const float4 v = reinterpret_cast<const float4*>(s)[i];
    __half2* d2 = reinterpret_cast<__half2*>(d);
    d2[2 * i]     = __floats2half2_rn(v.x, v.y);
    d2[2 * i + 1] = __floats2half2_rn(v.z, v.w);
}

// ============== CSR build via 2-level bucket sort (LDS atomics only) ========
__global__ __launch_bounds__(256) void bucket_count(
    const int* __restrict__ rows, int nnz, int nb, int* __restrict__ histT)
{
    __shared__ int cnt[NBUCK];
    for (int i = threadIdx.x; i < NBUCK; i += 256) cnt[i] = 0;
    __syncthreads();
    const int e0 = blockIdx.x * CHUNK;
    const int e1 = min(e0 + CHUNK, nnz);
    for (int e = e0 + threadIdx.x; e < e1; e += 256)
        atomicAdd(&cnt[rows[e] >> BUCKET_BITS], 1);
    __syncthreads();
    for (int b = threadIdx.x; b < NBUCK; b += 256)
        histT[b * nb + blockIdx.x] = cnt[b];
}

__global__ __launch_bounds__(1024) void scanA(
    const int* __restrict__ cnt, int* __restrict__ excl,
    int* __restrict__ blocksums, int n)
{
    const int t = threadIdx.x;
    const int gid = blockIdx.x * 1024 + t;
    const int lane = t & 63, wid = t >> 6;
    int v = (gid < n) ? cnt[gid] : 0;
    int x = v;
#pragma unroll
    for (int o = 1; o < 64; o <<= 1) {
        int y = __shfl_up(x, o, 64);
        if (lane >= o) x += y;
    }
    __shared__ int ws[16];
    __shared__ int wo[16];
    if (lane == 63) ws[wid] = x;
    __syncthreads();
    if (t < 16) {
        int s = ws[t];
        int xx = s;
#pragma unroll
        for (int o = 1; o < 16; o <<= 1) {
            int y = __shfl_up(xx, o, 16);
            if (t >= o) xx += y;
        }
        wo[t] = xx - s;
        if (t == 15) blocksums[blockIdx.x] = xx;
    }
    __syncthreads();
    if (gid < n) excl[gid] = x - v + wo[wid];
}

__global__ __launch_bounds__(1024) void scanB(int* __restrict__ bs, int nb)
{
    const int t = threadIdx.x;
    const int lane = t & 63, wid = t >> 6;
    int v = (t < nb) ? bs[t] : 0;
    int x = v;
#pragma unroll
    for (int o = 1; o < 64; o <<= 1) {
        int y = __shfl_up(x, o, 64);
        if (lane >= o) x += y;
    }
    __shared__ int ws[16];
    __shared__ int wo[16];
    if (lane == 63) ws[wid] = x;
    __syncthreads();
    if (t < 16) {
        int s = ws[t];
        int xx = s;
#pragma unroll
        for (int o = 1; o < 16; o <<= 1) {
            int y = __shfl_up(xx, o, 16);
            if (t >= o) xx += y;
        }
        wo[t] = xx - s;
    }
    __syncthreads();
    if (t < nb) bs[t] = x - v + wo[wid];
}

__global__ __launch_bounds__(256) void scan_apply(
    int* __restrict__ excl, const int* __restrict__ bo, int n)
{
    const int gid = blockIdx.x * blockDim.x + threadIdx.x;
    if (gid < n) excl[gid] += bo[gid >> 10];
}

__global__ __launch_bounds__(256) void bucket_place(
    const int* __restrict__ rows, const int* __restrict__ cols,
    const float* __restrict__ vals, int nnz, int nb,
    const int* __restrict__ offsT, uint2* __restrict__ rec)
{
    __shared__ int cur[NBUCK];
    for (int b = threadIdx.x; b < NBUCK; b += 256)
        cur[b] = offsT[b * nb + blockIdx.x];
    __syncthreads();
    const int e0 = blockIdx.x * CHUNK;
    const int e1 = min(e0 + CHUNK, nnz);
    for (int e = e0 + threadIdx.x; e < e1; e += 256) {
        const int r = rows[e];
        const int b = r >> BUCKET_BITS;
        const int pos = atomicAdd(&cur[b], 1);
        rec[pos] = make_uint2(((unsigned)cols[e] << BUCKET_BITS) |
                                  (unsigned)(r & (BROWS - 1)),
                              __float_as_uint(vals[e]));
    }
}

__global__ __launch_bounds__(1024) void bucket_finalize(
    const uint2* __restrict__ rec, int nnz, int nb,
    const int* __restrict__ offsT, int* __restrict__ rp,
    int2* __restrict__ ev)
{
    const int b = blockIdx.x;
    const int t = threadIdx.x;
    const int rlo = b << BUCKET_BITS;
    const int segs = offsT[b * nb];
    const int sege = (b + 1 < NBUCK) ? offsT[(b + 1) * nb] : nnz;

    __shared__ int cnt[BROWS];
    __shared__ int cur[BROWS];
    cnt[t] = 0;
    __syncthreads();
    for (int i = segs + t; i < sege; i += 1024)
        atomicAdd(&cnt[rec[i].x & (BROWS - 1)], 1);
    __syncthreads();

    const int lane = t & 63, wid = t >> 6;
    const int v = cnt[t];
    int x = v;
#pragma unroll
    for (int o = 1; o < 64; o <<= 1) {
        int y = __shfl_up(x, o, 64);
        if (lane >= o) x += y;
    }
    __shared__ int wsum[16];
    __shared__ int woff[16];
    if (lane == 63) wsum[wid] = x;
    __syncthreads();
    if (t < 16) {
        int s = wsum[t];
        int xx = s;
#pragma unroll
        for (int o = 1; o < 16; o <<= 1) {
            int y = __shfl_up(xx, o, 16);
            if (t >= o) xx += y;
        }
        woff[t] = xx - s;
    }
    __syncthreads();
    const int start = segs + (x - v + woff[wid]);

    if (rlo + t < NN) rp[rlo + t] = start;
    if (b == NBUCK - 1 && t == 0) rp[NN] = nnz;
    cur[t] = start;
    __syncthreads();

    for (int i = segs + t; i < sege; i += 1024) {
        const uint2 R = rec[i];
        const int rl = (int)(R.x & (BROWS - 1));
        const int c = (int)(R.x >> BUCKET_BITS);
        const int pos = atomicAdd(&cur[rl], 1);
        ev[pos] = make_int2(c, (int)R.y);
    }
}

// ---------------- CSR SPMM, fp16 gather sources, fp32 accumulate ------------
__global__ __launch_bounds__(256) void spmm_h(
    const int* __restrict__ rp, const int2* __restrict__ ev,
    const __half* __restrict__ srcU, const __half* __restrict__ srcI,
    float* __restrict__ out32, __half* __restrict__ out16,
    const float* __restrict__ add1, const float* __restrict__ add2)
{
    const int gid = blockIdx.x * blockDim.x + threadIdx.x;
    const int row = gid >> 6;
    const int lane = threadIdx.x & 63;
    if (row >= NN) return;
    const int s = rp[row], e = rp[row + 1];
    float acc = 0.f;
    int i = s;
    for (; i + 3 < e; i += 4) {
        const int2 e0 = ev[i], e1 = ev[i + 1], e2 = ev[i + 2], e3 = ev[i + 3];
        const __half* p0 = (e0.x < USER_N) ? (srcU + (size_t)e0.x * D)
                                           : (srcI + (size_t)(e0.x - USER_N) * D);
        const __half* p1 = (e1.x < USER_N) ? (srcU + (size_t)e1.x * D)
                                           : (srcI + (size_t)(e1.x - USER_N) * D);
        const __half* p2 = (e2.x < USER_N) ? (srcU + (size_t)e2.x * D)
                                           : (srcI + (size_t)(e2.x - USER_N) * D);
        const __half* p3 = (e3.x < USER_N) ? (srcU + (size_t)e3.x * D)
                                           : (srcI + (size_t)(e3.x - USER_N) * D);
        const float x0 = __half2float(p0[lane]);
        const float x1 = __half2float(p1[lane]);
        const float x2 = __half2float(p2[lane]);
        const float x3 = __half2float(p3[lane]);
        acc += __int_as_float(e0.y) * x0;
        acc += __int_as_float(e1.y) * x1;
        acc += __int_as_float(e2.y) * x2;
        acc += __int_as_float(e3.y) * x3;
    }
    for (; i < e; i++) {
        const int2 e0 = ev[i];
        const __half* p0 = (e0.x < USER_N) ? (srcU + (size_t)e0.x * D)
                                           : (srcI + (size_t)(e0.x - USER_N) * D);
        acc += __int_as_float(e0.y) * __half2float(p0[lane]);
    }
    const size_t idx = (size_t)row * D + lane;
    if (add1) acc += add1[idx];
    if (add2) acc += add2[idx];
    out32[idx] = acc;
    if (out16) out16[idx] = __float2half(acc);
}

// ---------------- fp32 CSR SPMM (fallback path, round-5 proven) -------------
__global__ __launch_bounds__(256) void spmm_csr(
    const int* __restrict__ rp, const int2* __restrict__ ev,
    const float* __restrict__ srcU, const float* __restrict__ srcI,
    float* __restrict__ out,
    const float* __restrict__ add1, const float* __restrict__ add2)
{
    const int gid = blockIdx.x * blockDim.x + threadIdx.x;
    const int row = gid >> 6;
    const int lane = threadIdx.x & 63;
    if (row >= NN) return;
    const int s = rp[row], e = rp[row + 1];
    float acc = 0.f;
    int i = s;
    for (; i + 3 < e; i += 4) {
        const int2 e0 = ev[i], e1 = ev[i + 1], e2 = ev[i + 2], e3 = ev[i + 3];
        const float* p0 = (e0.x < USER_N) ? (srcU + (size_t)e0.x * D)
                                          : (srcI + (size_t)(e0.x - USER_N) * D);
        const float* p1 = (e1.x < USER_N) ? (srcU + (size_t)e1.x * D)
                                          : (srcI + (size_t)(e1.x - USER_N) * D);
        const float* p2 = (e2.x < USER_N) ? (srcU + (size_t)e2.x * D)
                                          : (srcI + (size_t)(e2.x - USER_N) * D);
        const float* p3 = (e3.x < USER_N) ? (srcU + (size_t)e3.x * D)
                                          : (srcI + (size_t)(e3.x - USER_N) * D);
        acc += __int_as_float(e0.y) * p0[lane];
        acc += __int_as_float(e1.y) * p1[lane];
        acc += __int_as_float(e2.y) * p2[lane];
        acc += __int_as_float(e3.y) * p3[lane];
    }
    for (; i < e; i++) {
        const int2 e0 = ev[i];
        const float* p0 = (e0.x < USER_N) ? (srcU + (size_t)e0.x * D)
                                          : (srcI + (size_t)(e0.x - USER_N) * D);
        acc += __int_as_float(e0.y) * p0[lane];
    }
    const size_t idx = (size_t)row * D + lane;
    if (add1) acc += add1[idx];
    if (add2) acc += add2[idx];
    out[idx] = acc;
}

// fp32 rownorm (fallback)
__global__ __launch_bounds__(256) void rownorm(float* __restrict__ X, int nrows)
{
    const int gid = blockIdx.x * blockDim.x + threadIdx.x;
    const int row = gid >> 6;
    const int lane = threadIdx.x & 63;
    if (row >= nrows) return;
    float v = X[(size_t)row * D + lane];
    float s = v * v;
#pragma unroll
    for (int o = 32; o > 0; o >>= 1) s += __shfl_xor(s, o, 64);
    const float scale = 1.0f / fmaxf(sqrtf(s), 1e-12f);
    X[(size_t)row * D + lane] = v * scale;
}

extern "C" void kernel_launch(void* const* d_in, const int* in_sizes, int n_in,
                              void* d_out, int out_size, void* d_ws, size_t ws_size,
                              hipStream_t stream)
{
    const int*   adj_rows = (const int*)d_in[0];
    const int*   adj_cols = (const int*)d_in[1];
    const float* adj_vals = (const float*)d_in[2];
    const int*   img_rows = (const int*)d_in[3];
    const int*   img_cols = (const int*)d_in[4];
    const float* img_vals = (const float*)d_in[5];
    const float* img_emb  = (const float*)d_in[6];
    const float* uEmb     = (const float*)d_in[7];
    const float* iEmb     = (const float*)d_in[8];
    const float* Wt       = (const float*)d_in[9];
    const float* bt       = (const float*)d_in[10];
    float* out = (float*)d_out;

    const int e_adj = in_sizes[0];
    const int e_img = in_sizes[3];
    const int NB_adj = (e_adj + CHUNK - 1) / CHUNK;
    const int NB_img = (e_img + CHUNK - 1) / CHUNK;

    const size_t ndbytes = (size_t)NN * D * sizeof(float);
    const size_t nhbytes = (size_t)NN * D * sizeof(__half);

    // ---- workspace layout ----
    size_t off = 0;
    auto carve = [&](size_t bytes) { size_t p = off; off += (bytes + 15) & ~(size_t)15; return p; };
    char* base = (char*)d_ws;
    const size_t o_featsN = carve((size_t)ITEM_N * D * sizeof(float));
    const size_t o_bufA   = carve(ndbytes);
    const size_t o_bufB   = carve(ndbytes);
    const size_t o_rpAdj  = carve((NN + 1) * sizeof(int));
    const size_t o_rpImg  = carve((NN + 1) * sizeof(int));
    const size_t o_bsums  = carve(1024 * sizeof(int));
    const size_t o_histT  = carve((size_t)NBUCK * (NB_adj > NB_img ? NB_adj : NB_img) * sizeof(int));
    const size_t o_rec    = carve((size_t)(e_adj > e_img ? e_adj : e_img) * sizeof(uint2));  // -> h1 after build
    const size_t o_evAdj  = carve((size_t)e_adj * sizeof(int2));
    const size_t need_fp32_base = off;                 // (evImg carved below)
    const size_t o_evImg  = carve((size_t)e_img * sizeof(int2) > nhbytes
                                      ? (size_t)e_img * sizeof(int2) : nhbytes);  // -> h2 after g
    const size_t need_shared = off;
    const size_t o_ui16   = carve(nhbytes);
    const size_t o_f16    = carve((size_t)ITEM_N * D * sizeof(__half));
    const size_t need_h = off;
    (void)need_fp32_base;

    if (ws_size < need_shared) return;
    const bool use_h = (ws_size >= need_h);

    float* featsN = (float*)(base + o_featsN);
    float* bufA   = (float*)(base + o_bufA);
    float* bufB   = (float*)(base + o_bufB);
    int* rpAdj    = (int*)(base + o_rpAdj);
    int* rpImg    = (int*)(base + o_rpImg);
    int* bsums    = (int*)(base + o_bsums);
    int* histT    = (int*)(base + o_histT);
    uint2* rec    = (uint2*)(base + o_rec);
    int2* evAdj   = (int2*)(base + o_evAdj);
    int2* evImg   = (int2*)(base + o_evImg);
    __half* h1    = (__half*)(base + o_rec);    // alias: dead after builds
    __half* h2    = (__half*)(base + o_evImg);  // alias: dead after g-spmm
    __half* ui16  = (__half*)(base + o_ui16);
    __half* f16   = (__half*)(base + o_f16);

    // ---- build CSR for adj ----
    {
        const int n = NBUCK * NB_adj;
        const int nsb = (n + 1023) / 1024;
        bucket_count<<<NB_adj, 256, 0, stream>>>(adj_rows, e_adj, NB_adj, histT);
        scanA<<<nsb, 1024, 0, stream>>>(histT, histT, bsums, n);
        scanB<<<1, 1024, 0, stream>>>(bsums, nsb);
        scan_apply<<<(n + 255) / 256, 256, 0, stream>>>(histT, bsums, n);
        bucket_place<<<NB_adj, 256, 0, stream>>>(
            adj_rows, adj_cols, adj_vals, e_adj, NB_adj, histT, rec);
        bucket_finalize<<<NBUCK, 1024, 0, stream>>>(
            rec, e_adj, NB_adj, histT, rpAdj, evAdj);
    }
    // ---- build CSR for img ----
    {
        const int n = NBUCK * NB_img;
        const int nsb = (n + 1023) / 1024;
        bucket_count<<<NB_img, 256, 0, stream>>>(img_rows, e_img, NB_img, histT);
        scanA<<<nsb, 1024, 0, stream>>>(histT, histT, bsums, n);
        scanB<<<1, 1024, 0, stream>>>(bsums, nsb);
        scan_apply<<<(n + 255) / 256, 256, 0, stream>>>(histT, bsums, n);
        bucket_place<<<NB_img, 256, 0, stream>>>(
            img_rows, img_cols, img_vals, e_img, NB_img, histT, rec);
        bucket_finalize<<<NBUCK, 1024, 0, stream>>>(
            rec, e_img, NB_img, histT, rpImg, evImg);
    }

    const int SPMM_GRID = (NN * 64 + 255) / 256;
    const int RN_GRID = (ITEM_N * 64 + 255) / 256;

    if (use_h) {
        // fp16 source copies of [u;i]
        cvt_f2h<<<(USER_N * D / 4 + 255) / 256, 256, 0, stream>>>(
            uEmb, ui16, USER_N * D / 4);
        cvt_f2h<<<(ITEM_N * D / 4 + 255) / 256, 256, 0, stream>>>(
            iEmb, ui16 + (size_t)USER_N * D, ITEM_N * D / 4);

        gemm_feats<<<(ITEM_N + 63) / 64, 256, 0, stream>>>(img_emb, Wt, bt, featsN);
        rownorm_h<<<RN_GRID, 256, 0, stream>>>(featsN, f16, ITEM_N);

        // g = img_adj @ [u;i] -> bufA (fp32)          [evImg still live here]
        spmm_h<<<SPMM_GRID, 256, 0, stream>>>(
            rpImg, evImg, ui16, ui16 + (size_t)USER_N * D, bufA, nullptr,
            nullptr, nullptr);

        // e1 = adj @ [u; featsN] -> bufB + h1          [rec dead -> h1]
        spmm_h<<<SPMM_GRID, 256, 0, stream>>>(
            rpAdj, evAdj, ui16, f16, bufB, h1, nullptr, nullptr);

        // E = adj @ [e1_U; i] + e1 + g -> bufA + h2    [evImg dead -> h2]
        spmm_h<<<SPMM_GRID, 256, 0, stream>>>(
            rpAdj, evAdj, h1, ui16 + (size_t)USER_N * D, bufA, h2, bufB, bufA);

        // cur1 = adj @ E -> bufB + h1
        spmm_h<<<SPMM_GRID, 256, 0, stream>>>(
            rpAdj, evAdj, h2, h2 + (size_t)USER_N * D, bufB, h1,
            nullptr, nullptr);

        // out = adj @ cur1 + E + cur1
        spmm_h<<<SPMM_GRID, 256, 0, stream>>>(
            rpAdj, evAdj, h1, h1 + (size_t)USER_N * D, out, nullptr,
            bufA, bufB);
    } else {
        gemm_feats<<<(ITEM_N + 63) / 64, 256, 0, stream>>>(img_emb, Wt, bt, featsN);
        rownorm<<<RN_GRID, 256, 0, stream>>>(featsN, ITEM_N);

        spmm_csr<<<SPMM_GRID, 256, 0, stream>>>(
            rpImg, evImg, uEmb, iEmb, bufA, nullptr, nullptr);
        spmm_csr<<<SPMM_GRID, 256, 0, stream>>>(
            rpAdj, evAdj, uEmb, featsN, bufB, nullptr, nullptr);
        spmm_csr<<<SPMM_GRID, 256, 0, stream>>>(
            rpAdj, evAdj, bufB, iEmb, bufA, bufB, bufA);
        spmm_csr<<<SPMM_GRID, 256, 0, stream>>>(
            rpAdj, evAdj, bufA, bufA + (size_t)USER_N * D, bufB, nullptr, nullptr);
        spmm_csr<<<SPMM_GRID, 256, 0, stream>>>(
            rpAdj, evAdj, bufB, bufB + (size_t)USER_N * D, out, bufA, bufB);
    }
}

// Round 7
// 863.835 us; speedup vs baseline: 3.5731x; 1.0329x over previous
//
#include <hip/hip_runtime.h>
#include <hip/hip_fp16.h>

#define USER_N 100000
#define ITEM_N 50000
#define NN (USER_N + ITEM_N)
#define D 64
#define IMGD 1024
#define LDP 68

#define BUCKET_BITS 10
#define BROWS (1 << BUCKET_BITS)
#define NBUCK ((NN + BROWS - 1) >> BUCKET_BITS)   // 147
#define CHUNK 4096

// ------------- GEMM: C[ITEM,64] = A[ITEM,1024] @ W[1024,64] + b -------------
// 32x64 tile (grid 1563 = 6 blocks/CU; round-6's 64x64 was grid-limited at 3/CU)
__global__ __launch_bounds__(256) void gemm_feats32(
    const float* __restrict__ A, const float* __restrict__ W,
    const float* __restrict__ b, float* __restrict__ C)
{
    __shared__ float As[32][LDP];
    __shared__ float Ws[64][LDP];
    const int row0 = blockIdx.x * 32;
    const int t = threadIdx.x;
    const int tx = t & 15, ty = t >> 4;   // tx: col quad, ty: row pair
    float acc[2][4] = {};

    const int lr = t >> 4;        // 0..15
    const int lk = (t & 15) * 4;  // 0..60

    for (int k0 = 0; k0 < IMGD; k0 += 64) {
#pragma unroll
        for (int i = 0; i < 2; i++) {
            const int r = lr + i * 16;
            const int grow = row0 + r;
            float4 v = make_float4(0.f, 0.f, 0.f, 0.f);
            if (grow < ITEM_N)
                v = *reinterpret_cast<const float4*>(&A[(size_t)grow * IMGD + k0 + lk]);
            *reinterpret_cast<float4*>(&As[r][lk]) = v;
        }
#pragma unroll
        for (int i = 0; i < 4; i++) {
            const int kr = lr + i * 16;
            float4 v = *reinterpret_cast<const float4*>(&W[(size_t)(k0 + kr) * D + lk]);
            *reinterpret_cast<float4*>(&Ws[kr][lk]) = v;
        }
        __syncthreads();
#pragma unroll
        for (int kb = 0; kb < 16; kb++) {
            float a_[2][4], w_[4][4];
#pragma unroll
            for (int i = 0; i < 2; i++) {
                const float4 v = *reinterpret_cast<const float4*>(&As[ty * 2 + i][kb * 4]);
                a_[i][0] = v.x; a_[i][1] = v.y; a_[i][2] = v.z; a_[i][3] = v.w;
            }
#pragma unroll
            for (int j = 0; j < 4; j++) {
                const float4 v = *reinterpret_cast<const float4*>(&Ws[kb * 4 + j][tx * 4]);
                w_[j][0] = v.x; w_[j][1] = v.y; w_[j][2] = v.z; w_[j][3] = v.w;
            }
#pragma unroll
            for (int j = 0; j < 4; j++)
#pragma unroll
                for (int i = 0; i < 2; i++)
#pragma unroll
                    for (int c = 0; c < 4; c++)
                        acc[i][c] += a_[i][j] * w_[j][c];
        }
        __syncthreads();
    }
    const float4 bias = *reinterpret_cast<const float4*>(&b[tx * 4]);
#pragma unroll
    for (int i = 0; i < 2; i++) {
        const int grow = row0 + ty * 2 + i;
        if (grow < ITEM_N) {
            float4 v;
            v.x = acc[i][0] + bias.x;
            v.y = acc[i][1] + bias.y;
            v.z = acc[i][2] + bias.z;
            v.w = acc[i][3] + bias.w;
            *reinterpret_cast<float4*>(&C[(size_t)grow * D + tx * 4]) = v;
        }
    }
}

// ------------- Row L2 normalize -> fp16 output (one wave per row) -----------
__global__ __launch_bounds__(256) void rownorm_h(
    const float* __restrict__ X, __half* __restrict__ Y, int nrows)
{
    const int gid = blockIdx.x * blockDim.x + threadIdx.x;
    const int row = gid >> 6;
    const int lane = threadIdx.x & 63;
    if (row >= nrows) return;
    float v = X[(size_t)row * D + lane];
    float s = v * v;
#pragma unroll
    for (int o = 32; o > 0; o >>= 1) s += __shfl_xor(s, o, 64);
    const float scale = 1.0f / fmaxf(sqrtf(s), 1e-12f);
    Y[(size_t)row * D + lane] = __float2half(v * scale);
}

// fp32 rownorm (fallback)
__global__ __launch_bounds__(256) void rownorm(float* __restrict__ X, int nrows)
{
    const int gid = blockIdx.x * blockDim.x + threadIdx.x;
    const int row = gid >> 6;
    const int lane = threadIdx.x & 63;
    if (row >= nrows) return;
    float v = X[(size_t)row * D + lane];
    float s = v * v;
#pragma unroll
    for (int o = 32; o > 0; o >>= 1) s += __shfl_xor(s, o, 64);
    const float scale = 1.0f / fmaxf(sqrtf(s), 1e-12f);
    X[(size_t)row * D + lane] = v * scale;
}

// ------------- fp32 -> fp16 convert (float4 in, 2x half2 out) ---------------
__global__ __launch_bounds__(256) void cvt_f2h(
    const float* __restrict__ s, __half* __restrict__ d, int n4)
{
    const int i = blockIdx.x * blockDim.x + threadIdx.x;
    if (i >= n4) return;
    const float4 v = reinterpret_cast<const float4*>(s)[i];
    __half2* d2 = reinterpret_cast<__half2*>(d);
    d2[2 * i]     = __floats2half2_rn(v.x, v.y);
    d2[2 * i + 1] = __floats2half2_rn(v.z, v.w);
}

// ============== CSR build via 2-level bucket sort (LDS atomics only) ========
__global__ __launch_bounds__(256) void bucket_count(
    const int* __restrict__ rows, int nnz, int nb, int* __restrict__ histT)
{
    __shared__ int cnt[NBUCK];
    for (int i = threadIdx.x; i < NBUCK; i += 256) cnt[i] = 0;
    __syncthreads();
    const int e0 = blockIdx.x * CHUNK;
    const int e1 = min(e0 + CHUNK, nnz);
    for (int e = e0 + threadIdx.x; e < e1; e += 256)
        atomicAdd(&cnt[rows[e] >> BUCKET_BITS], 1);
    __syncthreads();
    for (int b = threadIdx.x; b < NBUCK; b += 256)
        histT[b * nb + blockIdx.x] = cnt[b];
}

__global__ __launch_bounds__(1024) void scanA(
    const int* __restrict__ cnt, int* __restrict__ excl,
    int* __restrict__ blocksums, int n)
{
    const int t = threadIdx.x;
    const int gid = blockIdx.x * 1024 + t;
    const int lane = t & 63, wid = t >> 6;
    int v = (gid < n) ? cnt[gid] : 0;
    int x = v;
#pragma unroll
    for (int o = 1; o < 64; o <<= 1) {
        int y = __shfl_up(x, o, 64);
        if (lane >= o) x += y;
    }
    __shared__ int ws[16];
    __shared__ int wo[16];
    if (lane == 63) ws[wid] = x;
    __syncthreads();
    if (t < 16) {
        int s = ws[t];
        int xx = s;
#pragma unroll
        for (int o = 1; o < 16; o <<= 1) {
            int y = __shfl_up(xx, o, 16);
            if (t >= o) xx += y;
        }
        wo[t] = xx - s;
        if (t == 15) blocksums[blockIdx.x] = xx;
    }
    __syncthreads();
    if (gid < n) excl[gid] = x - v + wo[wid];
}

__global__ __launch_bounds__(1024) void scanB(int* __restrict__ bs, int nb)
{
    const int t = threadIdx.x;
    const int lane = t & 63, wid = t >> 6;
    int v = (t < nb) ? bs[t] : 0;
    int x = v;
#pragma unroll
    for (int o = 1; o < 64; o <<= 1) {
        int y = __shfl_up(x, o, 64);
        if (lane >= o) x += y;
    }
    __shared__ int ws[16];
    __shared__ int wo[16];
    if (lane == 63) ws[wid] = x;
    __syncthreads();
    if (t < 16) {
        int s = ws[t];
        int xx = s;
#pragma unroll
        for (int o = 1; o < 16; o <<= 1) {
            int y = __shfl_up(xx, o, 16);
            if (t >= o) xx += y;
        }
        wo[t] = xx - s;
    }
    __syncthreads();
    if (t < nb) bs[t] = x - v + wo[wid];
}

__global__ __launch_bounds__(256) void scan_apply(
    int* __restrict__ excl, const int* __restrict__ bo, int n)
{
    const int gid = blockIdx.x * blockDim.x + threadIdx.x;
    if (gid < n) excl[gid] += bo[gid >> 10];
}

__global__ __launch_bounds__(256) void bucket_place(
    const int* __restrict__ rows, const int* __restrict__ cols,
    const float* __restrict__ vals, int nnz, int nb,
    const int* __restrict__ offsT, uint2* __restrict__ rec)
{
    __shared__ int cur[NBUCK];
    for (int b = threadIdx.x; b < NBUCK; b += 256)
        cur[b] = offsT[b * nb + blockIdx.x];
    __syncthreads();
    const int e0 = blockIdx.x * CHUNK;
    const int e1 = min(e0 + CHUNK, nnz);
    for (int e = e0 + threadIdx.x; e < e1; e += 256) {
        const int r = rows[e];
        const int b = r >> BUCKET_BITS;
        const int pos = atomicAdd(&cur[b], 1);
        rec[pos] = make_uint2(((unsigned)cols[e] << BUCKET_BITS) |
                                  (unsigned)(r & (BROWS - 1)),
                              __float_as_uint(vals[e]));
    }
}

__global__ __launch_bounds__(1024) void bucket_finalize(
    const uint2* __restrict__ rec, int nnz, int nb,
    const int* __restrict__ offsT, int* __restrict__ rp,
    int2* __restrict__ ev)
{
    const int b = blockIdx.x;
    const int t = threadIdx.x;
    const int rlo = b << BUCKET_BITS;
    const int segs = offsT[b * nb];
    const int sege = (b + 1 < NBUCK) ? offsT[(b + 1) * nb] : nnz;

    __shared__ int cnt[BROWS];
    __shared__ int cur[BROWS];
    cnt[t] = 0;
    __syncthreads();
    for (int i = segs + t; i < sege; i += 1024)
        atomicAdd(&cnt[rec[i].x & (BROWS - 1)], 1);
    __syncthreads();

    const int lane = t & 63, wid = t >> 6;
    const int v = cnt[t];
    int x = v;
#pragma unroll
    for (int o = 1; o < 64; o <<= 1) {
        int y = __shfl_up(x, o, 64);
        if (lane >= o) x += y;
    }
    __shared__ int wsum[16];
    __shared__ int woff[16];
    if (lane == 63) wsum[wid] = x;
    __syncthreads();
    if (t < 16) {
        int s = wsum[t];
        int xx = s;
#pragma unroll
        for (int o = 1; o < 16; o <<= 1) {
            int y = __shfl_up(xx, o, 16);
            if (t >= o) xx += y;
        }
        woff[t] = xx - s;
    }
    __syncthreads();
    const int start = segs + (x - v + woff[wid]);

    if (rlo + t < NN) rp[rlo + t] = start;
    if (b == NBUCK - 1 && t == 0) rp[NN] = nnz;
    cur[t] = start;
    __syncthreads();

    for (int i = segs + t; i < sege; i += 1024) {
        const uint2 R = rec[i];
        const int rl = (int)(R.x & (BROWS - 1));
        const int c = (int)(R.x >> BUCKET_BITS);
        const int pos = atomicAdd(&cur[rl], 1);
        ev[pos] = make_int2(c, (int)R.y);
    }
}

// ------- CSR SPMM v2: single concat fp16 src, 8-deep gather pipeline --------
__global__ __launch_bounds__(256) void spmm_h2(
    const int* __restrict__ rp, const int2* __restrict__ ev,
    const __half* __restrict__ src,
    float* __restrict__ out32, __half* __restrict__ out16, int limit16,
    const float* __restrict__ add1, const float* __restrict__ add2)
{
    const int gid = blockIdx.x * blockDim.x + threadIdx.x;
    const int row = gid >> 6;
    const int lane = threadIdx.x & 63;
    if (row >= NN) return;
    const int s = rp[row], e = rp[row + 1];
    float acc = 0.f;
    int i = s;
    for (; i + 7 < e; i += 8) {
        const int2 E0 = ev[i],     E1 = ev[i + 1], E2 = ev[i + 2], E3 = ev[i + 3];
        const int2 E4 = ev[i + 4], E5 = ev[i + 5], E6 = ev[i + 6], E7 = ev[i + 7];
        const float x0 = __half2float(src[(size_t)E0.x * D + lane]);
        const float x1 = __half2float(src[(size_t)E1.x * D + lane]);
        const float x2 = __half2float(src[(size_t)E2.x * D + lane]);
        const float x3 = __half2float(src[(size_t)E3.x * D + lane]);
        const float x4 = __half2float(src[(size_t)E4.x * D + lane]);
        const float x5 = __half2float(src[(size_t)E5.x * D + lane]);
        const float x6 = __half2float(src[(size_t)E6.x * D + lane]);
        const float x7 = __half2float(src[(size_t)E7.x * D + lane]);
        acc += __int_as_float(E0.y) * x0;
        acc += __int_as_float(E1.y) * x1;
        acc += __int_as_float(E2.y) * x2;
        acc += __int_as_float(E3.y) * x3;
        acc += __int_as_float(E4.y) * x4;
        acc += __int_as_float(E5.y) * x5;
        acc += __int_as_float(E6.y) * x6;
        acc += __int_as_float(E7.y) * x7;
    }
    for (; i < e; i++) {
        const int2 E0 = ev[i];
        acc += __int_as_float(E0.y) * __half2float(src[(size_t)E0.x * D + lane]);
    }
    const size_t idx = (size_t)row * D + lane;
    if (add1) acc += add1[idx];
    if (add2) acc += add2[idx];
    out32[idx] = acc;
    if (row < limit16) out16[idx] = __float2half(acc);
}

// ---------------- fp32 CSR SPMM (fallback path) -----------------------------
__global__ __launch_bounds__(256) void spmm_csr(
    const int* __restrict__ rp, const int2* __restrict__ ev,
    const float* __restrict__ srcU, const float* __restrict__ srcI,
    float* __restrict__ out,
    const float* __restrict__ add1, const float* __restrict__ add2)
{
    const int gid = blockIdx.x * blockDim.x + threadIdx.x;
    const int row = gid >> 6;
    const int lane = threadIdx.x & 63;
    if (row >= NN) return;
    const int s = rp[row], e = rp[row + 1];
    float acc = 0.f;
    int i = s;
    for (; i + 3 < e; i += 4) {
        const int2 e0 = ev[i], e1 = ev[i + 1], e2 = ev[i + 2], e3 = ev[i + 3];
        const float* p0 = (e0.x < USER_N) ? (srcU + (size_t)e0.x * D)
                                          : (srcI + (size_t)(e0.x - USER_N) * D);
        const float* p1 = (e1.x < USER_N) ? (srcU + (size_t)e1.x * D)
                                          : (srcI + (size_t)(e1.x - USER_N) * D);
        const float* p2 = (e2.x < USER_N) ? (srcU + (size_t)e2.x * D)
                                          : (srcI + (size_t)(e2.x - USER_N) * D);
        const float* p3 = (e3.x < USER_N) ? (srcU + (size_t)e3.x * D)
                                          : (srcI + (size_t)(e3.x - USER_N) * D);
        acc += __int_as_float(e0.y) * p0[lane];
        acc += __int_as_float(e1.y) * p1[lane];
        acc += __int_as_float(e2.y) * p2[lane];
        acc += __int_as_float(e3.y) * p3[lane];
    }
    for (; i < e; i++) {
        const int2 e0 = ev[i];
        const float* p0 = (e0.x < USER_N) ? (srcU + (size_t)e0.x * D)
                                          : (srcI + (size_t)(e0.x - USER_N) * D);
        acc += __int_as_float(e0.y) * p0[lane];
    }
    const size_t idx = (size_t)row * D + lane;
    if (add1) acc += add1[idx];
    if (add2) acc += add2[idx];
    out[idx] = acc;
}

extern "C" void kernel_launch(void* const* d_in, const int* in_sizes, int n_in,
                              void* d_out, int out_size, void* d_ws, size_t ws_size,
                              hipStream_t stream)
{
    const int*   adj_rows = (const int*)d_in[0];
    const int*   adj_cols = (const int*)d_in[1];
    const float* adj_vals = (const float*)d_in[2];
    const int*   img_rows = (const int*)d_in[3];
    const int*   img_cols = (const int*)d_in[4];
    const float* img_vals = (const float*)d_in[5];
    const float* img_emb  = (const float*)d_in[6];
    const float* uEmb     = (const float*)d_in[7];
    const float* iEmb     = (const float*)d_in[8];
    const float* Wt       = (const float*)d_in[9];
    const float* bt       = (const float*)d_in[10];
    float* out = (float*)d_out;

    const int e_adj = in_sizes[0];
    const int e_img = in_sizes[3];
    const int e_max = e_adj > e_img ? e_adj : e_img;
    const int NB_adj = (e_adj + CHUNK - 1) / CHUNK;
    const int NB_img = (e_img + CHUNK - 1) / CHUNK;
    const int NB_max = NB_adj > NB_img ? NB_adj : NB_img;

    const size_t ndbytes = (size_t)NN * D * sizeof(float);
    const size_t nhbytes = (size_t)NN * D * sizeof(__half);

    // ---- workspace layout (aliased: rec->xC, evImg->xB, x0->xA/xD) ----
    size_t off = 0;
    auto carve = [&](size_t bytes) { size_t p = off; off += (bytes + 255) & ~(size_t)255; return p; };
    char* base = (char*)d_ws;
    const size_t o_featsN = carve((size_t)ITEM_N * D * sizeof(float));
    const size_t o_bufA   = carve(ndbytes);
    const size_t o_bufB   = carve(ndbytes);
    const size_t o_rpAdj  = carve((NN + 1) * sizeof(int));
    const size_t o_rpImg  = carve((NN + 1) * sizeof(int));
    const size_t o_bsums  = carve(1024 * sizeof(int));
    const size_t o_histT  = carve((size_t)NBUCK * NB_max * sizeof(int));
    const size_t o_rec    = carve((size_t)e_max * sizeof(uint2) > nhbytes
                                      ? (size_t)e_max * sizeof(uint2) : nhbytes);
    const size_t o_evAdj  = carve((size_t)e_adj * sizeof(int2));
    const size_t need_base = off;
    const size_t o_evImg  = carve((size_t)e_img * sizeof(int2) > nhbytes
                                      ? (size_t)e_img * sizeof(int2) : nhbytes);
    const size_t o_x0     = carve(nhbytes);
    const size_t need_h = off;

    if (ws_size < need_base) return;
    const bool use_h = (ws_size >= need_h);

    float* featsN = (float*)(base + o_featsN);
    float* bufA   = (float*)(base + o_bufA);
    float* bufB   = (float*)(base + o_bufB);
    int* rpAdj    = (int*)(base + o_rpAdj);
    int* rpImg    = (int*)(base + o_rpImg);
    int* bsums    = (int*)(base + o_bsums);
    int* histT    = (int*)(base + o_histT);
    uint2* rec    = (uint2*)(base + o_rec);
    int2* evAdj   = (int2*)(base + o_evAdj);
    int2* evImg   = (int2*)(base + o_evImg);
    __half* xC    = (__half*)(base + o_rec);    // alias: rec dead after builds
    __half* xB    = (__half*)(base + o_evImg);  // alias: evImg dead after g
    __half* x0    = (__half*)(base + o_x0);     // xAll0 / xA / xD

    // ---- build CSR for adj ----
    {
        const int n = NBUCK * NB_adj;
        const int nsb = (n + 1023) / 1024;
        bucket_count<<<NB_adj, 256, 0, stream>>>(adj_rows, e_adj, NB_adj, histT);
        scanA<<<nsb, 1024, 0, stream>>>(histT, histT, bsums, n);
        scanB<<<1, 1024, 0, stream>>>(bsums, nsb);
        scan_apply<<<(n + 255) / 256, 256, 0, stream>>>(histT, bsums, n);
        bucket_place<<<NB_adj, 256, 0, stream>>>(
            adj_rows, adj_cols, adj_vals, e_adj, NB_adj, histT, rec);
        bucket_finalize<<<NBUCK, 1024, 0, stream>>>(
            rec, e_adj, NB_adj, histT, rpAdj, evAdj);
    }
    // ---- build CSR for img ----
    {
        const int n = NBUCK * NB_img;
        const int nsb = (n + 1023) / 1024;
        bucket_count<<<NB_img, 256, 0, stream>>>(img_rows, e_img, NB_img, histT);
        scanA<<<nsb, 1024, 0, stream>>>(histT, histT, bsums, n);
        scanB<<<1, 1024, 0, stream>>>(bsums, nsb);
        scan_apply<<<(n + 255) / 256, 256, 0, stream>>>(histT, bsums, n);
        bucket_place<<<NB_img, 256, 0, stream>>>(
            img_rows, img_cols, img_vals, e_img, NB_img, histT, rec);
        bucket_finalize<<<NBUCK, 1024, 0, stream>>>(
            rec, e_img, NB_img, histT, rpImg, evImg);
    }

    const int SPMM_GRID = (NN * 64 + 255) / 256;
    const int RN_GRID = (ITEM_N * 64 + 255) / 256;
    const int GEMM_GRID = (ITEM_N + 31) / 32;

    if (use_h) {
        __half* x0I = x0 + (size_t)USER_N * D;
        __half* xBI = xB + (size_t)USER_N * D;

        // x0 = [u16; i16]
        cvt_f2h<<<(USER_N * D / 4 + 255) / 256, 256, 0, stream>>>(
            uEmb, x0, USER_N * D / 4);
        cvt_f2h<<<(ITEM_N * D / 4 + 255) / 256, 256, 0, stream>>>(
            iEmb, x0I, ITEM_N * D / 4);

        // g = img_adj @ [u;i] -> bufA     (last reader of evImg)
        spmm_h2<<<SPMM_GRID, 256, 0, stream>>>(
            rpImg, evImg, x0, bufA, nullptr, 0, nullptr, nullptr);

        // feats; x0 item half <- normalized feats  (x0 becomes [u16; featsN16])
        gemm_feats32<<<GEMM_GRID, 256, 0, stream>>>(img_emb, Wt, bt, featsN);
        rownorm_h<<<RN_GRID, 256, 0, stream>>>(featsN, x0I, ITEM_N);

        // xB item half <- i16 (evImg region now dead)
        cvt_f2h<<<(ITEM_N * D / 4 + 255) / 256, 256, 0, stream>>>(
            iEmb, xBI, ITEM_N * D / 4);

        // e1 = adj @ x0 -> bufB; fp16 user rows -> xB  (xB = [e1_U; i16])
        spmm_h2<<<SPMM_GRID, 256, 0, stream>>>(
            rpAdj, evAdj, x0, bufB, xB, USER_N, nullptr, nullptr);

        // E = adj @ xB + e1 + g -> bufA; fp16 -> xC
        spmm_h2<<<SPMM_GRID, 256, 0, stream>>>(
            rpAdj, evAdj, xB, bufA, xC, NN, bufB, bufA);

        // cur1 = adj @ xC -> bufB; fp16 -> x0 (dead as e1-source now)
        spmm_h2<<<SPMM_GRID, 256, 0, stream>>>(
            rpAdj, evAdj, xC, bufB, x0, NN, nullptr, nullptr);

        // out = adj @ x0 + E + cur1
        spmm_h2<<<SPMM_GRID, 256, 0, stream>>>(
            rpAdj, evAdj, x0, out, nullptr, 0, bufA, bufB);
    } else {
        gemm_feats32<<<GEMM_GRID, 256, 0, stream>>>(img_emb, Wt, bt, featsN);
        rownorm<<<RN_GRID, 256, 0, stream>>>(featsN, ITEM_N);

        spmm_csr<<<SPMM_GRID, 256, 0, stream>>>(
            rpImg, evImg, uEmb, iEmb, bufA, nullptr, nullptr);
        spmm_csr<<<SPMM_GRID, 256, 0, stream>>>(
            rpAdj, evAdj, uEmb, featsN, bufB, nullptr, nullptr);
        spmm_csr<<<SPMM_GRID, 256, 0, stream>>>(
            rpAdj, evAdj, bufB, iEmb, bufA, bufB, bufA);
        spmm_csr<<<SPMM_GRID, 256, 0, stream>>>(
            rpAdj, evAdj, bufA, bufA + (size_t)USER_N * D, bufB, nullptr, nullptr);
        spmm_csr<<<SPMM_GRID, 256, 0, stream>>>(
            rpAdj, evAdj, bufB, bufB + (size_t)USER_N * D, out, bufA, bufB);
    }
}

// Round 8
// 595.819 us; speedup vs baseline: 5.1804x; 1.4498x over previous
//
#include <hip/hip_runtime.h>
#include <hip/hip_fp16.h>

#define USER_N 100000
#define ITEM_N 50000
#define NN (USER_N + ITEM_N)
#define D 64
#define IMGD 1024
#define LDP 68

#define BUCKET_BITS 10
#define BROWS (1 << BUCKET_BITS)
#define NBUCK ((NN + BROWS - 1) >> BUCKET_BITS)   // 147
#define CHUNK 4096

// ------------- GEMM: C[ITEM,64] = A[ITEM,1024] @ W[1024,64] + b -------------
__global__ __launch_bounds__(256) void gemm_feats32(
    const float* __restrict__ A, const float* __restrict__ W,
    const float* __restrict__ b, float* __restrict__ C)
{
    __shared__ float As[32][LDP];
    __shared__ float Ws[64][LDP];
    const int row0 = blockIdx.x * 32;
    const int t = threadIdx.x;
    const int tx = t & 15, ty = t >> 4;
    float acc[2][4] = {};

    const int lr = t >> 4;
    const int lk = (t & 15) * 4;

    for (int k0 = 0; k0 < IMGD; k0 += 64) {
#pragma unroll
        for (int i = 0; i < 2; i++) {
            const int r = lr + i * 16;
            const int grow = row0 + r;
            float4 v = make_float4(0.f, 0.f, 0.f, 0.f);
            if (grow < ITEM_N)
                v = *reinterpret_cast<const float4*>(&A[(size_t)grow * IMGD + k0 + lk]);
            *reinterpret_cast<float4*>(&As[r][lk]) = v;
        }
#pragma unroll
        for (int i = 0; i < 4; i++) {
            const int kr = lr + i * 16;
            float4 v = *reinterpret_cast<const float4*>(&W[(size_t)(k0 + kr) * D + lk]);
            *reinterpret_cast<float4*>(&Ws[kr][lk]) = v;
        }
        __syncthreads();
#pragma unroll
        for (int kb = 0; kb < 16; kb++) {
            float a_[2][4], w_[4][4];
#pragma unroll
            for (int i = 0; i < 2; i++) {
                const float4 v = *reinterpret_cast<const float4*>(&As[ty * 2 + i][kb * 4]);
                a_[i][0] = v.x; a_[i][1] = v.y; a_[i][2] = v.z; a_[i][3] = v.w;
            }
#pragma unroll
            for (int j = 0; j < 4; j++) {
                const float4 v = *reinterpret_cast<const float4*>(&Ws[kb * 4 + j][tx * 4]);
                w_[j][0] = v.x; w_[j][1] = v.y; w_[j][2] = v.z; w_[j][3] = v.w;
            }
#pragma unroll
            for (int j = 0; j < 4; j++)
#pragma unroll
                for (int i = 0; i < 2; i++)
#pragma unroll
                    for (int c = 0; c < 4; c++)
                        acc[i][c] += a_[i][j] * w_[j][c];
        }
        __syncthreads();
    }
    const float4 bias = *reinterpret_cast<const float4*>(&b[tx * 4]);
#pragma unroll
    for (int i = 0; i < 2; i++) {
        const int grow = row0 + ty * 2 + i;
        if (grow < ITEM_N) {
            float4 v;
            v.x = acc[i][0] + bias.x;
            v.y = acc[i][1] + bias.y;
            v.z = acc[i][2] + bias.z;
            v.w = acc[i][3] + bias.w;
            *reinterpret_cast<float4*>(&C[(size_t)grow * D + tx * 4]) = v;
        }
    }
}

// ------------- Row L2 normalize -> fp16 output ------------------------------
__global__ __launch_bounds__(256) void rownorm_h(
    const float* __restrict__ X, __half* __restrict__ Y, int nrows)
{
    const int gid = blockIdx.x * blockDim.x + threadIdx.x;
    const int row = gid >> 6;
    const int lane = threadIdx.x & 63;
    if (row >= nrows) return;
    float v = X[(size_t)row * D + lane];
    float s = v * v;
#pragma unroll
    for (int o = 32; o > 0; o >>= 1) s += __shfl_xor(s, o, 64);
    const float scale = 1.0f / fmaxf(sqrtf(s), 1e-12f);
    Y[(size_t)row * D + lane] = __float2half(v * scale);
}

__global__ __launch_bounds__(256) void rownorm(float* __restrict__ X, int nrows)
{
    const int gid = blockIdx.x * blockDim.x + threadIdx.x;
    const int row = gid >> 6;
    const int lane = threadIdx.x & 63;
    if (row >= nrows) return;
    float v = X[(size_t)row * D + lane];
    float s = v * v;
#pragma unroll
    for (int o = 32; o > 0; o >>= 1) s += __shfl_xor(s, o, 64);
    const float scale = 1.0f / fmaxf(sqrtf(s), 1e-12f);
    X[(size_t)row * D + lane] = v * scale;
}

__global__ __launch_bounds__(256) void cvt_f2h(
    const float* __restrict__ s, __half* __restrict__ d, int n4)
{
    const int i = blockIdx.x * blockDim.x + threadIdx.x;
    if (i >= n4) return;
    const float4 v = reinterpret_cast<const float4*>(s)[i];
    __half2* d2 = reinterpret_cast<__half2*>(d);
    d2[2 * i]     = __floats2half2_rn(v.x, v.y);
    d2[2 * i + 1] = __floats2half2_rn(v.z, v.w);
}

// ============== CSR build via 2-level bucket sort (LDS atomics only) ========
__global__ __launch_bounds__(256) void bucket_count(
    const int* __restrict__ rows, int nnz, int nb, int* __restrict__ histT)
{
    __shared__ int cnt[NBUCK];
    for (int i = threadIdx.x; i < NBUCK; i += 256) cnt[i] = 0;
    __syncthreads();
    const int e0 = blockIdx.x * CHUNK;
    const int e1 = min(e0 + CHUNK, nnz);
    for (int e = e0 + threadIdx.x; e < e1; e += 256)
        atomicAdd(&cnt[rows[e] >> BUCKET_BITS], 1);
    __syncthreads();
    for (int b = threadIdx.x; b < NBUCK; b += 256)
        histT[b * nb + blockIdx.x] = cnt[b];
}

__global__ __launch_bounds__(1024) void scanA(
    const int* __restrict__ cnt, int* __restrict__ excl,
    int* __restrict__ blocksums, int n)
{
    const int t = threadIdx.x;
    const int gid = blockIdx.x * 1024 + t;
    const int lane = t & 63, wid = t >> 6;
    int v = (gid < n) ? cnt[gid] : 0;
    int x = v;
#pragma unroll
    for (int o = 1; o < 64; o <<= 1) {
        int y = __shfl_up(x, o, 64);
        if (lane >= o) x += y;
    }
    __shared__ int ws[16];
    __shared__ int wo[16];
    if (lane == 63) ws[wid] = x;
    __syncthreads();
    if (t < 16) {
        int s = ws[t];
        int xx = s;
#pragma unroll
        for (int o = 1; o < 16; o <<= 1) {
            int y = __shfl_up(xx, o, 16);
            if (t >= o) xx += y;
        }
        wo[t] = xx - s;
        if (t == 15) blocksums[blockIdx.x] = xx;
    }
    __syncthreads();
    if (gid < n) excl[gid] = x - v + wo[wid];
}

__global__ __launch_bounds__(1024) void scanB(int* __restrict__ bs, int nb)
{
    const int t = threadIdx.x;
    const int lane = t & 63, wid = t >> 6;
    int v = (t < nb) ? bs[t] : 0;
    int x = v;
#pragma unroll
    for (int o = 1; o < 64; o <<= 1) {
        int y = __shfl_up(x, o, 64);
        if (lane >= o) x += y;
    }
    __shared__ int ws[16];
    __shared__ int wo[16];
    if (lane == 63) ws[wid] = x;
    __syncthreads();
    if (t < 16) {
        int s = ws[t];
        int xx = s;
#pragma unroll
        for (int o = 1; o < 16; o <<= 1) {
            int y = __shfl_up(xx, o, 16);
            if (t >= o) xx += y;
        }
        wo[t] = xx - s;
    }
    __syncthreads();
    if (t < nb) bs[t] = x - v + wo[wid];
}

__global__ __launch_bounds__(256) void scan_apply(
    int* __restrict__ excl, const int* __restrict__ bo, int n)
{
    const int gid = blockIdx.x * blockDim.x + threadIdx.x;
    if (gid < n) excl[gid] += bo[gid >> 10];
}

__global__ __launch_bounds__(256) void bucket_place(
    const int* __restrict__ rows, const int* __restrict__ cols,
    const float* __restrict__ vals, int nnz, int nb,
    const int* __restrict__ offsT, uint2* __restrict__ rec)
{
    __shared__ int cur[NBUCK];
    for (int b = threadIdx.x; b < NBUCK; b += 256)
        cur[b] = offsT[b * nb + blockIdx.x];
    __syncthreads();
    const int e0 = blockIdx.x * CHUNK;
    const int e1 = min(e0 + CHUNK, nnz);
    for (int e = e0 + threadIdx.x; e < e1; e += 256) {
        const int r = rows[e];
        const int b = r >> BUCKET_BITS;
        const int pos = atomicAdd(&cur[b], 1);
        rec[pos] = make_uint2(((unsigned)cols[e] << BUCKET_BITS) |
                                  (unsigned)(r & (BROWS - 1)),
                              __float_as_uint(vals[e]));
    }
}

__global__ __launch_bounds__(1024) void bucket_finalize(
    const uint2* __restrict__ rec, int nnz, int nb,
    const int* __restrict__ offsT, int* __restrict__ rp,
    int2* __restrict__ ev)
{
    const int b = blockIdx.x;
    const int t = threadIdx.x;
    const int rlo = b << BUCKET_BITS;
    const int segs = offsT[b * nb];
    const int sege = (b + 1 < NBUCK) ? offsT[(b + 1) * nb] : nnz;

    __shared__ int cnt[BROWS];
    __shared__ int cur[BROWS];
    cnt[t] = 0;
    __syncthreads();
    for (int i = segs + t; i < sege; i += 1024)
        atomicAdd(&cnt[rec[i].x & (BROWS - 1)], 1);
    __syncthreads();

    const int lane = t & 63, wid = t >> 6;
    const int v = cnt[t];
    int x = v;
#pragma unroll
    for (int o = 1; o < 64; o <<= 1) {
        int y = __shfl_up(x, o, 64);
        if (lane >= o) x += y;
    }
    __shared__ int wsum[16];
    __shared__ int woff[16];
    if (lane == 63) wsum[wid] = x;
    __syncthreads();
    if (t < 16) {
        int s = wsum[t];
        int xx = s;
#pragma unroll
        for (int o = 1; o < 16; o <<= 1) {
            int y = __shfl_up(xx, o, 16);
            if (t >= o) xx += y;
        }
        woff[t] = xx - s;
    }
    __syncthreads();
    const int start = segs + (x - v + woff[wid]);

    if (rlo + t < NN) rp[rlo + t] = start;
    if (b == NBUCK - 1 && t == 0) rp[NN] = nnz;
    cur[t] = start;
    __syncthreads();

    for (int i = segs + t; i < sege; i += 1024) {
        const uint2 R = rec[i];
        const int rl = (int)(R.x & (BROWS - 1));
        const int c = (int)(R.x >> BUCKET_BITS);
        const int pos = atomicAdd(&cur[rl], 1);
        ev[pos] = make_int2(c, (int)R.y);
    }
}

// ------- CSR SPMM v4: 4 rows per wave (16 lanes x 8B per row) ---------------
// Cuts wave count 4x: per-row serial gather chains were the limiter (time was
// proportional to rows, not edges — r7 counters).
__global__ __launch_bounds__(256) void spmm_h4(
    const int* __restrict__ rp, const int2* __restrict__ ev,
    const __half* __restrict__ src,
    float* __restrict__ out32, __half* __restrict__ out16, int limit16,
    const float* __restrict__ add1, const float* __restrict__ add2)
{
    const int wid = (blockIdx.x * 256 + threadIdx.x) >> 6;
    const int lane = threadIdx.x & 63;
    const int sub = lane >> 4;      // row within wave: 0..3
    const int l16 = lane & 15;      // 16 lanes per row, 4 dims each
    const int rowbase = wid * 4;
    if (rowbase >= NN) return;
    const int row = rowbase + sub;

    int v = 0;
    if (lane <= 4 && rowbase + lane <= NN) v = rp[rowbase + lane];
    const int s = __shfl(v, sub, 64);
    const int e = __shfl(v, sub + 1, 64);

    const __half* srcl = src + l16 * 4;
    float4 acc = make_float4(0.f, 0.f, 0.f, 0.f);

    union cvt { unsigned u; __half2 h; };
    int i = s;
    for (; i + 3 < e; i += 4) {
        const int2 E0 = ev[i], E1 = ev[i + 1], E2 = ev[i + 2], E3 = ev[i + 3];
        const uint2 g0 = *reinterpret_cast<const uint2*>(srcl + (size_t)E0.x * D);
        const uint2 g1 = *reinterpret_cast<const uint2*>(srcl + (size_t)E1.x * D);
        const uint2 g2 = *reinterpret_cast<const uint2*>(srcl + (size_t)E2.x * D);
        const uint2 g3 = *reinterpret_cast<const uint2*>(srcl + (size_t)E3.x * D);
#pragma unroll
        for (int k = 0; k < 4; k++) {
            const uint2 g = k == 0 ? g0 : k == 1 ? g1 : k == 2 ? g2 : g3;
            const float w = __int_as_float(k == 0 ? E0.y : k == 1 ? E1.y
                                           : k == 2 ? E2.y : E3.y);
            cvt c0, c1; c0.u = g.x; c1.u = g.y;
            const float2 f0 = __half22float2(c0.h);
            const float2 f1 = __half22float2(c1.h);
            acc.x += w * f0.x;
            acc.y += w * f0.y;
            acc.z += w * f1.x;
            acc.w += w * f1.y;
        }
    }
    for (; i < e; i++) {
        const int2 E0 = ev[i];
        const uint2 g = *reinterpret_cast<const uint2*>(srcl + (size_t)E0.x * D);
        const float w = __int_as_float(E0.y);
        cvt c0, c1; c0.u = g.x; c1.u = g.y;
        const float2 f0 = __half22float2(c0.h);
        const float2 f1 = __half22float2(c1.h);
        acc.x += w * f0.x;
        acc.y += w * f0.y;
        acc.z += w * f1.x;
        acc.w += w * f1.y;
    }

    if (row >= NN) return;
    const size_t idx = (size_t)row * D + l16 * 4;
    if (add1) {
        const float4 a = *reinterpret_cast<const float4*>(&add1[idx]);
        acc.x += a.x; acc.y += a.y; acc.z += a.z; acc.w += a.w;
    }
    if (add2) {
        const float4 a = *reinterpret_cast<const float4*>(&add2[idx]);
        acc.x += a.x; acc.y += a.y; acc.z += a.z; acc.w += a.w;
    }
    *reinterpret_cast<float4*>(&out32[idx]) = acc;
    if (row < limit16) {
        const __half2 o0 = __floats2half2_rn(acc.x, acc.y);
        const __half2 o1 = __floats2half2_rn(acc.z, acc.w);
        cvt c0, c1; c0.h = o0; c1.h = o1;
        *reinterpret_cast<uint2*>(&out16[idx]) = make_uint2(c0.u, c1.u);
    }
}

// ---------------- fp32 CSR SPMM (fallback path) -----------------------------
__global__ __launch_bounds__(256) void spmm_csr(
    const int* __restrict__ rp, const int2* __restrict__ ev,
    const float* __restrict__ srcU, const float* __restrict__ srcI,
    float* __restrict__ out,
    const float* __restrict__ add1, const float* __restrict__ add2)
{
    const int gid = blockIdx.x * blockDim.x + threadIdx.x;
    const int row = gid >> 6;
    const int lane = threadIdx.x & 63;
    if (row >= NN) return;
    const int s = rp[row], e = rp[row + 1];
    float acc = 0.f;
    int i = s;
    for (; i + 3 < e; i += 4) {
        const int2 e0 = ev[i], e1 = ev[i + 1], e2 = ev[i + 2], e3 = ev[i + 3];
        const float* p0 = (e0.x < USER_N) ? (srcU + (size_t)e0.x * D)
                                          : (srcI + (size_t)(e0.x - USER_N) * D);
        const float* p1 = (e1.x < USER_N) ? (srcU + (size_t)e1.x * D)
                                          : (srcI + (size_t)(e1.x - USER_N) * D);
        const float* p2 = (e2.x < USER_N) ? (srcU + (size_t)e2.x * D)
                                          : (srcI + (size_t)(e2.x - USER_N) * D);
        const float* p3 = (e3.x < USER_N) ? (srcU + (size_t)e3.x * D)
                                          : (srcI + (size_t)(e3.x - USER_N) * D);
        acc += __int_as_float(e0.y) * p0[lane];
        acc += __int_as_float(e1.y) * p1[lane];
        acc += __int_as_float(e2.y) * p2[lane];
        acc += __int_as_float(e3.y) * p3[lane];
    }
    for (; i < e; i++) {
        const int2 e0 = ev[i];
        const float* p0 = (e0.x < USER_N) ? (srcU + (size_t)e0.x * D)
                                          : (srcI + (size_t)(e0.x - USER_N) * D);
        acc += __int_as_float(e0.y) * p0[lane];
    }
    const size_t idx = (size_t)row * D + lane;
    if (add1) acc += add1[idx];
    if (add2) acc += add2[idx];
    out[idx] = acc;
}

extern "C" void kernel_launch(void* const* d_in, const int* in_sizes, int n_in,
                              void* d_out, int out_size, void* d_ws, size_t ws_size,
                              hipStream_t stream)
{
    const int*   adj_rows = (const int*)d_in[0];
    const int*   adj_cols = (const int*)d_in[1];
    const float* adj_vals = (const float*)d_in[2];
    const int*   img_rows = (const int*)d_in[3];
    const int*   img_cols = (const int*)d_in[4];
    const float* img_vals = (const float*)d_in[5];
    const float* img_emb  = (const float*)d_in[6];
    const float* uEmb     = (const float*)d_in[7];
    const float* iEmb     = (const float*)d_in[8];
    const float* Wt       = (const float*)d_in[9];
    const float* bt       = (const float*)d_in[10];
    float* out = (float*)d_out;

    const int e_adj = in_sizes[0];
    const int e_img = in_sizes[3];
    const int e_max = e_adj > e_img ? e_adj : e_img;
    const int NB_adj = (e_adj + CHUNK - 1) / CHUNK;
    const int NB_img = (e_img + CHUNK - 1) / CHUNK;
    const int NB_max = NB_adj > NB_img ? NB_adj : NB_img;

    const size_t ndbytes = (size_t)NN * D * sizeof(float);
    const size_t nhbytes = (size_t)NN * D * sizeof(__half);

    // ---- workspace layout (aliased: rec->xC, evImg->xB) ----
    size_t off = 0;
    auto carve = [&](size_t bytes) { size_t p = off; off += (bytes + 255) & ~(size_t)255; return p; };
    char* base = (char*)d_ws;
    const size_t o_featsN = carve((size_t)ITEM_N * D * sizeof(float));
    const size_t o_bufA   = carve(ndbytes);
    const size_t o_bufB   = carve(ndbytes);
    const size_t o_rpAdj  = carve((NN + 1) * sizeof(int));
    const size_t o_rpImg  = carve((NN + 1) * sizeof(int));
    const size_t o_bsums  = carve(1024 * sizeof(int));
    const size_t o_histT  = carve((size_t)NBUCK * NB_max * sizeof(int));
    const size_t o_rec    = carve((size_t)e_max * sizeof(uint2) > nhbytes
                                      ? (size_t)e_max * sizeof(uint2) : nhbytes);
    const size_t o_evAdj  = carve((size_t)e_adj * sizeof(int2));
    const size_t need_base = off;
    const size_t o_evImg  = carve((size_t)e_img * sizeof(int2) > nhbytes
                                      ? (size_t)e_img * sizeof(int2) : nhbytes);
    const size_t o_x0     = carve(nhbytes);
    const size_t need_h = off;

    if (ws_size < need_base) return;
    const bool use_h = (ws_size >= need_h);

    float* featsN = (float*)(base + o_featsN);
    float* bufA   = (float*)(base + o_bufA);
    float* bufB   = (float*)(base + o_bufB);
    int* rpAdj    = (int*)(base + o_rpAdj);
    int* rpImg    = (int*)(base + o_rpImg);
    int* bsums    = (int*)(base + o_bsums);
    int* histT    = (int*)(base + o_histT);
    uint2* rec    = (uint2*)(base + o_rec);
    int2* evAdj   = (int2*)(base + o_evAdj);
    int2* evImg   = (int2*)(base + o_evImg);
    __half* xC    = (__half*)(base + o_rec);    // alias: rec dead after builds
    __half* xB    = (__half*)(base + o_evImg);  // alias: evImg dead after g
    __half* x0    = (__half*)(base + o_x0);

    // ---- build CSR for adj ----
    {
        const int n = NBUCK * NB_adj;
        const int nsb = (n + 1023) / 1024;
        bucket_count<<<NB_adj, 256, 0, stream>>>(adj_rows, e_adj, NB_adj, histT);
        scanA<<<nsb, 1024, 0, stream>>>(histT, histT, bsums, n);
        scanB<<<1, 1024, 0, stream>>>(bsums, nsb);
        scan_apply<<<(n + 255) / 256, 256, 0, stream>>>(histT, bsums, n);
        bucket_place<<<NB_adj, 256, 0, stream>>>(
            adj_rows, adj_cols, adj_vals, e_adj, NB_adj, histT, rec);
        bucket_finalize<<<NBUCK, 1024, 0, stream>>>(
            rec, e_adj, NB_adj, histT, rpAdj, evAdj);
    }
    // ---- build CSR for img ----
    {
        const int n = NBUCK * NB_img;
        const int nsb = (n + 1023) / 1024;
        bucket_count<<<NB_img, 256, 0, stream>>>(img_rows, e_img, NB_img, histT);
        scanA<<<nsb, 1024, 0, stream>>>(histT, histT, bsums, n);
        scanB<<<1, 1024, 0, stream>>>(bsums, nsb);
        scan_apply<<<(n + 255) / 256, 256, 0, stream>>>(histT, bsums, n);
        bucket_place<<<NB_img, 256, 0, stream>>>(
            img_rows, img_cols, img_vals, e_img, NB_img, histT, rec);
        bucket_finalize<<<NBUCK, 1024, 0, stream>>>(
            rec, e_img, NB_img, histT, rpImg, evImg);
    }

    const int SPMM4_GRID = (NN + 15) / 16;   // 4 waves/block, 4 rows/wave
    const int SPMM_GRID = (NN * 64 + 255) / 256;
    const int RN_GRID = (ITEM_N * 64 + 255) / 256;
    const int GEMM_GRID = (ITEM_N + 31) / 32;

    if (use_h) {
        __half* x0I = x0 + (size_t)USER_N * D;
        __half* xBI = xB + (size_t)USER_N * D;

        // x0 = [u16; i16]
        cvt_f2h<<<(USER_N * D / 4 + 255) / 256, 256, 0, stream>>>(
            uEmb, x0, USER_N * D / 4);
        cvt_f2h<<<(ITEM_N * D / 4 + 255) / 256, 256, 0, stream>>>(
            iEmb, x0I, ITEM_N * D / 4);

        // g = img_adj @ [u;i] -> bufA     (last reader of evImg)
        spmm_h4<<<SPMM4_GRID, 256, 0, stream>>>(
            rpImg, evImg, x0, bufA, nullptr, 0, nullptr, nullptr);

        // feats; x0 item half <- normalized feats
        gemm_feats32<<<GEMM_GRID, 256, 0, stream>>>(img_emb, Wt, bt, featsN);
        rownorm_h<<<RN_GRID, 256, 0, stream>>>(featsN, x0I, ITEM_N);

        // xB item half <- i16 (evImg region now dead)
        cvt_f2h<<<(ITEM_N * D / 4 + 255) / 256, 256, 0, stream>>>(
            iEmb, xBI, ITEM_N * D / 4);

        // e1 = adj @ x0 -> bufB; fp16 user rows -> xB  (xB = [e1_U; i16])
        spmm_h4<<<SPMM4_GRID, 256, 0, stream>>>(
            rpAdj, evAdj, x0, bufB, xB, USER_N, nullptr, nullptr);

        // E = adj @ xB + e1 + g -> bufA; fp16 -> xC
        spmm_h4<<<SPMM4_GRID, 256, 0, stream>>>(
            rpAdj, evAdj, xB, bufA, xC, NN, bufB, bufA);

        // cur1 = adj @ xC -> bufB; fp16 -> x0
        spmm_h4<<<SPMM4_GRID, 256, 0, stream>>>(
            rpAdj, evAdj, xC, bufB, x0, NN, nullptr, nullptr);

        // out = adj @ x0 + E + cur1
        spmm_h4<<<SPMM4_GRID, 256, 0, stream>>>(
            rpAdj, evAdj, x0, out, nullptr, 0, bufA, bufB);
    } else {
        gemm_feats32<<<GEMM_GRID, 256, 0, stream>>>(img_emb, Wt, bt, featsN);
        rownorm<<<RN_GRID, 256, 0, stream>>>(featsN, ITEM_N);

        spmm_csr<<<SPMM_GRID, 256, 0, stream>>>(
            rpImg, evImg, uEmb, iEmb, bufA, nullptr, nullptr);
        spmm_csr<<<SPMM_GRID, 256, 0, stream>>>(
            rpAdj, evAdj, uEmb, featsN, bufB, nullptr, nullptr);
        spmm_csr<<<SPMM_GRID, 256, 0, stream>>>(
            rpAdj, evAdj, bufB, iEmb, bufA, bufB, bufA);
        spmm_csr<<<SPMM_GRID, 256, 0, stream>>>(
            rpAdj, evAdj, bufA, bufA + (size_t)USER_N * D, bufB, nullptr, nullptr);
        spmm_csr<<<SPMM_GRID, 256, 0, stream>>>(
            rpAdj, evAdj, bufB, bufB + (size_t)USER_N * D, out, bufA, bufB);
    }
}